// Round 8
// baseline (1406.423 us; speedup 1.0000x reference)
//
#include <hip/hip_runtime.h>
#include <math.h>

typedef __attribute__((ext_vector_type(8))) _Float16 f16x8;
typedef __attribute__((ext_vector_type(4))) float f32x4;

// ---------- fp16 helpers ----------
__device__ __forceinline__ ushort f2h(float x) {
  union { _Float16 h; ushort u; } c;
  c.h = (_Float16)x;
  return c.u;
}
__device__ __forceinline__ void gl_lds16(const ushort* g, ushort* l) {
  __builtin_amdgcn_global_load_lds(
      (const __attribute__((address_space(1))) unsigned int*)g,
      (__attribute__((address_space(3))) unsigned int*)l, 16, 0, 0);
}
__device__ __forceinline__ f32x4 mfma16(f16x8 a, f16x8 b, f32x4 c) {
  return __builtin_amdgcn_mfma_f32_16x16x32_f16(a, b, c, 0, 0, 0);
}

// ---------- block-wide sum reduce (256 threads = 4 waves) ----------
__device__ __forceinline__ float block_reduce_sum(float v, float* sb) {
#pragma unroll
  for (int o = 32; o > 0; o >>= 1) v += __shfl_down(v, o, 64);
  const int t = threadIdx.x;
  if ((t & 63) == 0) sb[t >> 6] = v;
  __syncthreads();
  v = sb[0] + sb[1] + sb[2] + sb[3];
  __syncthreads();
  return v;
}

// ---------- activation cast: fp32 -> fp16 plane ----------
__global__ __launch_bounds__(256) void acast(const float* __restrict__ X,
                                             ushort* __restrict__ H, int n4) {
  const int i = blockIdx.x * 256 + threadIdx.x;
  if (i >= n4) return;
  const float4 x = ((const float4*)X)[i];
  ushort4 h;
  h.x = f2h(x.x); h.y = f2h(x.y); h.z = f2h(x.z); h.w = f2h(x.w);
  ((ushort4*)H)[i] = h;
}

// ---------- bias concat for fused QKV ----------
__global__ __launch_bounds__(256) void concat3(const float* __restrict__ a,
                                               const float* __restrict__ b,
                                               const float* __restrict__ c,
                                               float* __restrict__ o) {
  const int i = blockIdx.x * 256 + threadIdx.x;  // 0..3071
  o[i] = i < 1024 ? a[i] : (i < 2048 ? b[i - 1024] : c[i - 2048]);
}

// ---------- weight transpose+cast: W[K,N] fp32 -> T [N,K] fp16 ----------
__global__ __launch_bounds__(256) void wcast_t(const float* __restrict__ W,
                                               ushort* __restrict__ T,
                                               int K, int N) {
  __shared__ float s[32][33];
  const int tx = threadIdx.x & 31, ty = threadIdx.x >> 5;
  const int n0 = blockIdx.x * 32, k0 = blockIdx.y * 32;
#pragma unroll
  for (int i = 0; i < 4; ++i)
    s[ty + i * 8][tx] = W[(size_t)(k0 + ty + i * 8) * N + n0 + tx];
  __syncthreads();
#pragma unroll
  for (int i = 0; i < 4; ++i) {
    const int n = ty + i * 8;
    T[(size_t)(n0 + n) * K + k0 + tx] = f2h(s[tx][n]);
  }
}

// ---------- fused QKV weight transpose (3x 1024x1024) ----------
__global__ __launch_bounds__(256) void wcast_t3(const float* __restrict__ W0,
                                                const float* __restrict__ W1,
                                                const float* __restrict__ W2,
                                                ushort* __restrict__ T) {
  __shared__ float s[32][33];
  const float* W = blockIdx.z == 0 ? W0 : (blockIdx.z == 1 ? W1 : W2);
  ushort* Tp = T + (size_t)blockIdx.z * 1024 * 1024;
  const int tx = threadIdx.x & 31, ty = threadIdx.x >> 5;
  const int n0 = blockIdx.x * 32, k0 = blockIdx.y * 32;
#pragma unroll
  for (int i = 0; i < 4; ++i)
    s[ty + i * 8][tx] = W[(size_t)(k0 + ty + i * 8) * 1024 + n0 + tx];
  __syncthreads();
#pragma unroll
  for (int i = 0; i < 4; ++i) {
    const int n = ty + i * 8;
    Tp[(size_t)(n0 + n) * 1024 + k0 + tx] = f2h(s[tx][n]);
  }
}

// ---------- fp16 MFMA GEMM, 128x128 tile, BK=32, 3-buf counted-vmcnt pipe ----
// 4 waves as 2x2, 16 MFMA per wave per K-step; prefetch depth 2 (T4).
// EPI: 1 bias+GELU->plane O | 2 bias+res->C (KSPLIT: z0->C w/ bias+res, z1 raw->C2)
//      5 QKV fused: col<2048 -> Q/K planes [2][4096][1024]; col>=2048 ->
//        transposed V plane at O+8M: [(b*32+h)*32+d][512]
template <int EPI, int KSPLIT>
__global__ __launch_bounds__(256, 2) void gemm_mfma(
    const ushort* __restrict__ A, const ushort* __restrict__ B,
    const float* __restrict__ bias, const float* __restrict__ res,
    float* __restrict__ C, float* __restrict__ C2, ushort* __restrict__ O,
    int M, int N, int K) {
  __shared__ __align__(16) ushort sA[3][4096], sB[3][4096];
  const int t = threadIdx.x, w = t >> 6, lane = t & 63;
  const int llo = lane & 15, lhi = lane >> 4;
  const int wm = w >> 1, wn = w & 1;
  const int z = (KSPLIT > 1) ? blockIdx.z : 0;
  const int Ks = K / KSPLIT;

  // XCD-aware bijective swizzle over (x,y); all grids have nwg % 8 == 0
  const int gx = gridDim.x;
  int wg = blockIdx.y * gx + blockIdx.x;
  const int nwg = gx * gridDim.y;
  wg = (wg & 7) * (nwg >> 3) + (wg >> 3);
  const int bm = (wg / gx) * 128, bn = (wg % gx) * 128;

  const ushort* pA0 = A + (size_t)(bm + lane) * K + w * 8 + z * Ks;
  const ushort* pA1 = pA0 + (size_t)64 * K;
  const ushort* pB0 = B + (size_t)(bn + lane) * K + w * 8 + z * Ks;
  const ushort* pB1 = pB0 + (size_t)64 * K;

  auto STAGE = [&](int buf, int k0) {
    gl_lds16(pA0 + k0, &sA[buf][w * 1024]);
    gl_lds16(pA1 + k0, &sA[buf][w * 1024 + 512]);
    gl_lds16(pB0 + k0, &sB[buf][w * 1024]);
    gl_lds16(pB1 + k0, &sB[buf][w * 1024 + 512]);
  };

  f32x4 acc[4][4] = {};
  const int NT = Ks >> 5;  // >= 16 for all our shapes
  STAGE(0, 0);
  STAGE(1, 32);
  STAGE(2, 64);
  int cur = 0;
  for (int kt = 0; kt < NT; ++kt) {
    // wait for stage kt only: 4 loads/wave/stage; stages kt+1, kt+2 stay in flight
    if (kt + 2 < NT)
      asm volatile("s_waitcnt vmcnt(8)" ::: "memory");
    else if (kt + 1 < NT)
      asm volatile("s_waitcnt vmcnt(4)" ::: "memory");
    else
      asm volatile("s_waitcnt vmcnt(0)" ::: "memory");
    asm volatile("s_barrier" ::: "memory");  // all waves' stage-kt data in LDS

    f16x8 a[4], bfr[4];
#pragma unroll
    for (int f = 0; f < 4; ++f) {
      a[f] = *(const f16x8*)&sA[cur][lhi * 1024 + (wm * 64 + f * 16 + llo) * 8];
      bfr[f] = *(const f16x8*)&sB[cur][lhi * 1024 + (wn * 64 + f * 16 + llo) * 8];
    }
#pragma unroll
    for (int fm = 0; fm < 4; ++fm)
#pragma unroll
      for (int fn = 0; fn < 4; ++fn)
        acc[fm][fn] = mfma16(a[fm], bfr[fn], acc[fm][fn]);

    asm volatile("s_barrier" ::: "memory");  // all reads of buf[cur] done
    if (kt + 3 < NT) STAGE(cur, (kt + 3) << 5);  // overwrite just-read buffer
    cur = (cur == 2) ? 0 : cur + 1;
  }

  // epilogue: C/D map col = lane&15, row = (lane>>4)*4 + r
#pragma unroll
  for (int fm = 0; fm < 4; ++fm) {
    const int row0 = bm + wm * 64 + fm * 16 + lhi * 4;
#pragma unroll
    for (int fn = 0; fn < 4; ++fn) {
      const int col = bn + wn * 64 + fn * 16 + llo;
      const float bc = bias[col];
      if (EPI == 5) {
        if (col < 2048) {
          const size_t base = (size_t)(col >> 10) * (4096 * 1024) + (col & 1023);
#pragma unroll
          for (int r = 0; r < 4; ++r)
            O[base + (size_t)(row0 + r) * 1024] = f2h(acc[fm][fn][r] + bc);
        } else {
          const int c = col - 2048;
          ushort4 vh;
#pragma unroll
          for (int r = 0; r < 4; ++r) ((ushort*)&vh)[r] = f2h(acc[fm][fn][r] + bc);
          const size_t o = (size_t)8 * 1024 * 1024 +
              ((size_t)(((row0 >> 9) * 32 + (c >> 5)) * 32 + (c & 31))) * 512 +
              (row0 & 511);
          *(ushort4*)(O + o) = vh;
        }
      } else if (EPI == 2) {
#pragma unroll
        for (int r = 0; r < 4; ++r) {
          const size_t o = (size_t)(row0 + r) * N + col;
          if (KSPLIT == 1 || z == 0)
            C[o] = acc[fm][fn][r] + bc + res[o];
          else
            C2[o] = acc[fm][fn][r];
        }
      } else {  // EPI == 1: GELU -> fp16 plane
#pragma unroll
        for (int r = 0; r < 4; ++r) {
          const size_t o = (size_t)(row0 + r) * N + col;
          float v = acc[fm][fn][r] + bc;
          v = 0.5f * v * (1.f + erff(v * 0.70710678118654752f));
          O[o] = f2h(v);
        }
      }
    }
  }
}

// ---------- fp16 MFMA flash attention per (b,h,zhalf): 512 threads ----------
// Swapped QK^T (S^T = K.Q^T); K slab [oct4][512][8]; V^T slab [koct64][32][8].
__global__ __launch_bounds__(512, 2) void attn_mfma(
    const ushort* __restrict__ Qg, const ushort* __restrict__ Kg,
    const ushort* __restrict__ Vg, const float* __restrict__ mask,
    const float* __restrict__ rel_l, ushort* __restrict__ Cg) {
  __shared__ __align__(16) ushort sK[16384], sV[16384];
  __shared__ __align__(16) ushort sP[5120];
  __shared__ float rel_s[1024];
  __shared__ float madd[512];

  const int h = blockIdx.x, b = blockIdx.y, z = blockIdx.z;
  const int t = threadIdx.x, w = t >> 6, lane = t & 63;
  const int llo = lane & 15, lhi = lane >> 4;
  const float SCALE = 0.17677669529663687f;  // 1/sqrt(32)

#pragma unroll
  for (int it = 0; it < 4; ++it) {
    const int task = t + it * 512;  // 0..2047
    const int s = task >> 2, oct = task & 3;
    const size_t g = (size_t)(b * 512 + s) * 1024 + h * 32 + oct * 8;
    *(uint4*)&sK[oct * 4096 + s * 8] = *(const uint4*)(Kg + g);
  }
#pragma unroll
  for (int it = 0; it < 4; ++it) {
    const int task = t + it * 512;  // 0..2047
    const int d = task >> 6, ko = task & 63;
    const size_t g = (size_t)((b * 32 + h) * 32 + d) * 512 + ko * 8;
    *(uint4*)&sV[ko * 256 + d * 8] = *(const uint4*)(Vg + g);
  }
  for (int i = t; i < 1023; i += 512) rel_s[i] = rel_l[(size_t)i * 32 + h];
  for (int i = t; i < 512; i += 512) madd[i] = (1.f - mask[b * 512 + i]) * -1e9f;
  __syncthreads();

  uint* wP = (uint*)(sP + w * 640 + llo * 40);
  const ushort* rP = sP + w * 640 + llo * 40;

  for (int qt = 0; qt < 2; ++qt) {
    const int q = z * 256 + w * 32 + qt * 16 + llo;
    const size_t qg = (size_t)(b * 512 + q) * 1024 + h * 32 + lhi * 8;
    const f16x8 fQ = *(const f16x8*)(Qg + qg);
    float m = -INFINITY, l = 0.f;
    f32x4 acc0 = {0.f, 0.f, 0.f, 0.f};
    f32x4 acc1 = {0.f, 0.f, 0.f, 0.f};

    for (int kt2 = 0; kt2 < 16; ++kt2) {
      float p[8];
      float tm = -INFINITY;
#pragma unroll
      for (int sub = 0; sub < 2; ++sub) {
        const int kt = kt2 * 2 + sub;
        const f16x8 fK = *(const f16x8*)&sK[lhi * 4096 + (kt * 16 + llo) * 8];
        f32x4 s4 = {0.f, 0.f, 0.f, 0.f};
        s4 = mfma16(fK, fQ, s4);
#pragma unroll
        for (int r = 0; r < 4; ++r) {
          const int k = kt * 16 + lhi * 4 + r;
          const float sv = (s4[r] + rel_s[q - k + 511]) * SCALE + madd[k];
          p[sub * 4 + r] = sv;
          tm = fmaxf(tm, sv);
        }
      }
      tm = fmaxf(tm, __shfl_xor(tm, 16));
      tm = fmaxf(tm, __shfl_xor(tm, 32));
      const float nm = fmaxf(m, tm);
      const float sc = __expf(m - nm);
      float ts = 0.f;
#pragma unroll
      for (int i = 0; i < 8; ++i) {
        p[i] = __expf(p[i] - nm);
        ts += p[i];
      }
      ts += __shfl_xor(ts, 16);
      ts += __shfl_xor(ts, 32);
      l = l * sc + ts;
      m = nm;
      acc0 *= sc;
      acc1 *= sc;
      // pack P into wave-private LDS in B-frag layout (fp16)
#pragma unroll
      for (int sub = 0; sub < 2; ++sub) {
        wP[sub * 8 + lhi * 2 + 0] =
            (uint)f2h(p[sub * 4 + 0]) | ((uint)f2h(p[sub * 4 + 1]) << 16);
        wP[sub * 8 + lhi * 2 + 1] =
            (uint)f2h(p[sub * 4 + 2]) | ((uint)f2h(p[sub * 4 + 3]) << 16);
      }
      const f16x8 fP = *(const f16x8*)(rP + lhi * 8);
      const int vb = (kt2 * 4 + lhi) * 256;
      const f16x8 fV0 = *(const f16x8*)&sV[vb + llo * 8];
      const f16x8 fV1 = *(const f16x8*)&sV[vb + (16 + llo) * 8];
      acc0 = mfma16(fV0, fP, acc0);
      acc1 = mfma16(fV1, fP, acc1);
    }

    const float invl = 1.f / l;
    const size_t ob = (size_t)(b * 512 + q) * 1024 + h * 32;
    ushort4 oh;
#pragma unroll
    for (int r = 0; r < 4; ++r) ((ushort*)&oh)[r] = f2h(acc0[r] * invl);
    *(ushort4*)(Cg + ob + lhi * 4) = oh;
#pragma unroll
    for (int r = 0; r < 4; ++r) ((ushort*)&oh)[r] = f2h(acc1[r] * invl);
    *(ushort4*)(Cg + ob + 16 + lhi * 4) = oh;
  }
}

// ---------- LayerNorm over rows of 1024 (optional 2nd addend, fp16 plane) ----
__global__ __launch_bounds__(256) void ln_kernel(
    const float* __restrict__ X, const float* __restrict__ X2,
    const float* __restrict__ g, const float* __restrict__ bt,
    float* __restrict__ out, ushort* __restrict__ O) {
  __shared__ float sb[4];
  const int row = blockIdx.x, t = threadIdx.x;
  float4 x = *(const float4*)&X[(size_t)row * 1024 + t * 4];
  if (X2) {
    const float4 y = *(const float4*)&X2[(size_t)row * 1024 + t * 4];
    x.x += y.x; x.y += y.y; x.z += y.z; x.w += y.w;
  }
  const float s = block_reduce_sum(x.x + x.y + x.z + x.w, sb);
  const float mu = s * (1.f / 1024.f);
  const float dx = x.x - mu, dy = x.y - mu, dz = x.z - mu, dw = x.w - mu;
  const float ss = block_reduce_sum(dx * dx + dy * dy + dz * dz + dw * dw, sb);
  const float rs = rsqrtf(ss * (1.f / 1024.f) + 1e-12f);
  const float4 gv = *(const float4*)&g[t * 4];
  const float4 bv = *(const float4*)&bt[t * 4];
  float4 o;
  o.x = dx * rs * gv.x + bv.x;
  o.y = dy * rs * gv.y + bv.y;
  o.z = dz * rs * gv.z + bv.z;
  o.w = dw * rs * gv.w + bv.w;
  *(float4*)&out[(size_t)row * 1024 + t * 4] = o;
  if (O) {
    ushort4 vh;
    vh.x = f2h(o.x); vh.y = f2h(o.y); vh.z = f2h(o.z); vh.w = f2h(o.w);
    *(ushort4*)&O[(size_t)row * 1024 + t * 4] = vh;
  }
}

// ---------- pooling stage 1: s-split partials ----------
__global__ __launch_bounds__(128) void pool_part(
    const float* __restrict__ X, const float* __restrict__ mask,
    float* __restrict__ psum, float* __restrict__ pmax,
    float* __restrict__ pcnt) {
  const int cb = blockIdx.x, b = blockIdx.y, sb = blockIdx.z;
  const int col = cb * 128 + threadIdx.x;
  float sum = 0.f, mx = -INFINITY, cnt = 0.f;
  for (int i = 0; i < 128; ++i) {
    const int s = sb * 128 + i;
    const float v = X[(size_t)(b * 512 + s) * 1024 + col];
    const float mk = mask[b * 512 + s];
    sum = fmaf(v, mk, sum);
    cnt += mk;
    mx = fmaxf(mx, v + (1.f - mk) * -1e9f);
  }
  psum[(size_t)(sb * 8 + b) * 1024 + col] = sum;
  pmax[(size_t)(sb * 8 + b) * 1024 + col] = mx;
  if (cb == 0 && threadIdx.x == 0) pcnt[sb * 8 + b] = cnt;
}

// ---------- pooling finalize: mean + max + first token ----------
__global__ __launch_bounds__(256) void pool_fin(
    const float* __restrict__ X, const float* __restrict__ psum,
    const float* __restrict__ pmax, const float* __restrict__ pcnt,
    float* __restrict__ pooled) {
  const int idx = blockIdx.x * 256 + threadIdx.x;  // 0..8191
  const int b = idx >> 10, col = idx & 1023;
  float s = 0.f, m = -INFINITY, c = 0.f;
#pragma unroll
  for (int sb = 0; sb < 4; ++sb) {
    s += psum[(size_t)(sb * 8 + b) * 1024 + col];
    m = fmaxf(m, pmax[(size_t)(sb * 8 + b) * 1024 + col]);
    c += pcnt[sb * 8 + b];
  }
  pooled[(size_t)b * 3072 + col] = s / c;
  pooled[(size_t)b * 3072 + 1024 + col] = m;
  pooled[(size_t)b * 3072 + 2048 + col] = X[(size_t)(b * 512) * 1024 + col];
}

// ---------- pooled GEMM stage 1: split-K partials ----------
__global__ __launch_bounds__(256) void pgemm_part(
    const float* __restrict__ P, const float* __restrict__ W,
    float* __restrict__ part) {
  __shared__ float sP[8][192];
  __shared__ float sacc[256][9];
  const int nb = blockIdx.x, kb = blockIdx.y;
  const int t = threadIdx.x;
  const int k0 = kb * 192, n0 = nb * 64;
  for (int i = t; i < 1536; i += 256)
    sP[i / 192][i % 192] = P[(size_t)(i / 192) * 3072 + k0 + i % 192];
  __syncthreads();
  const int n = t & 63, kq = t >> 6;
  float acc[8] = {};
  for (int kk = 0; kk < 48; ++kk) {
    const int k = kq * 48 + kk;
    const float wv = W[(size_t)(k0 + k) * 1024 + n0 + n];
#pragma unroll
    for (int b = 0; b < 8; ++b) acc[b] = fmaf(sP[b][k], wv, acc[b]);
  }
#pragma unroll
  for (int b = 0; b < 8; ++b) sacc[t][b] = acc[b];
  __syncthreads();
  for (int p = t; p < 512; p += 256) {
    const int b = p >> 6, nn = p & 63;
    const float v = sacc[nn][b] + sacc[64 + nn][b] + sacc[128 + nn][b] +
                    sacc[192 + nn][b];
    part[((size_t)kb * 8 + b) * 1024 + n0 + nn] = v;
  }
}

// ---------- pooled GEMM finalize ----------
__global__ __launch_bounds__(256) void pgemm_fin(
    const float* __restrict__ part, const float* __restrict__ bias,
    float* __restrict__ out) {
  const int idx = blockIdx.x * 256 + threadIdx.x;  // 0..8191
  const int b = idx >> 10, n = idx & 1023;
  float v = bias[n];
#pragma unroll
  for (int kb = 0; kb < 16; ++kb) v += part[((size_t)kb * 8 + b) * 1024 + n];
  out[(size_t)b * 1024 + n] = v;
}

// ---------- classifier: one block per (n,b), wave-reduce over K ----------
__global__ __launch_bounds__(64) void cls_kernel(
    const float* __restrict__ X, const float* __restrict__ W,
    const float* __restrict__ bias, float* __restrict__ out) {
  const int n = blockIdx.x, b = blockIdx.y, lane = threadIdx.x;
  float a = 0.f;
#pragma unroll
  for (int i = 0; i < 16; ++i) {
    const int k = lane + i * 64;
    a = fmaf(X[(size_t)b * 1024 + k], W[(size_t)k * 20 + n], a);
  }
#pragma unroll
  for (int o = 32; o > 0; o >>= 1) a += __shfl_down(a, o, 64);
  if (lane == 0) out[b * 20 + n] = a + bias[n];
}

extern "C" void kernel_launch(void* const* d_in, const int* in_sizes, int n_in,
                              void* d_out, int out_size, void* d_ws, size_t ws_size,
                              hipStream_t stream) {
  const float* hs    = (const float*)d_in[0];
  const float* amask = (const float*)d_in[1];
  const float* Wq    = (const float*)d_in[2];
  const float* bq    = (const float*)d_in[3];
  const float* Wk    = (const float*)d_in[4];
  const float* bk    = (const float*)d_in[5];
  const float* Wv    = (const float*)d_in[6];
  const float* bv    = (const float*)d_in[7];
  const float* Wo    = (const float*)d_in[8];
  const float* bo    = (const float*)d_in[9];
  const float* ln1g  = (const float*)d_in[10];
  const float* ln1b  = (const float*)d_in[11];
  const float* W1    = (const float*)d_in[12];
  const float* b1    = (const float*)d_in[13];
  const float* W2    = (const float*)d_in[14];
  const float* b2    = (const float*)d_in[15];
  const float* ln2g  = (const float*)d_in[16];
  const float* ln2b  = (const float*)d_in[17];
  const float* rel   = (const float*)d_in[18];
  const float* poolW = (const float*)d_in[19];
  const float* poolb = (const float*)d_in[20];
  const float* plng  = (const float*)d_in[21];
  const float* plnb  = (const float*)d_in[22];
  const float* clsW  = (const float*)d_in[23];
  const float* clsb  = (const float*)d_in[24];

  char* W = (char*)d_ws;
  const size_t MB = (size_t)1 << 20;
  const size_t QK = (size_t)4096 * 1024;  // Q/K plane stride (elements)
  float* buf_t  = (float*)(W + 0 * MB);    // 16MB fp32
  float* buf_t2 = (float*)(W + 16 * MB);   // 16MB fp32 (split-K partials)
  float* buf_h1 = (float*)(W + 32 * MB);   // 16MB fp32
  float* buf_x  = (float*)(W + 48 * MB);   // 16MB fp32
  ushort* PL  = (ushort*)(W + 64 * MB);    // Q(0..4M) K(4..8M) V^T(8..12M), 24MB
  ushort* CTX = (ushort*)(W + 88 * MB);    // 8MB; also next-layer X plane
  ushort* Xp  = CTX;
  ushort* H1  = (ushort*)(W + 96 * MB);    // 8MB
  ushort* F1  = (ushort*)(W + 104 * MB);   // 32MB
  ushort* Wt  = (ushort*)(W + 136 * MB);   // 6MB ([3072][1024] fp16)
  float* bcat = (float*)(W + 142 * MB);    // 12KB
  float* sm   = (float*)(W + 143 * MB);    // small-buffer region (<1.5MB)
  float* pooled  = sm;                     // 8*3072
  float* pool_h  = pooled + 8 * 3072;      // 8*1024
  float* pool_h2 = pool_h + 8 * 1024;      // 8*1024
  float* pcnt    = pool_h2 + 8 * 1024;     // 32
  float* psum    = pcnt + 64;              // 4*8*1024
  float* pmax    = psum + 4 * 8 * 1024;    // 4*8*1024
  float* pgpart  = pmax + 4 * 8 * 1024;    // 16*8*1024

  const int n4act = (4096 * 1024) / 4;
  const dim3 gQKV(3072 / 128, 32);     // 768 blocks
  const dim3 gF1(4096 / 128, 32);      // 1024 blocks
  const dim3 gKS(1024 / 128, 32, 2);   // 512 blocks (Wo, FFN2 split-K)
  const dim3 wsQ3(32, 32, 3);

  acast<<<n4act / 256, 256, 0, stream>>>(hs, Xp, n4act);

  const float* x_in = hs;
  for (int l = 0; l < 4; ++l) {
    const float* Wq_l = Wq + (size_t)l * 1024 * 1024;
    const float* Wk_l = Wk + (size_t)l * 1024 * 1024;
    const float* Wv_l = Wv + (size_t)l * 1024 * 1024;
    const float* Wo_l = Wo + (size_t)l * 1024 * 1024;
    const float* W1_l = W1 + (size_t)l * 1024 * 4096;
    const float* W2_l = W2 + (size_t)l * 4096 * 1024;

    // fused QKV
    concat3<<<12, 256, 0, stream>>>(bq + l * 1024, bk + l * 1024, bv + l * 1024, bcat);
    wcast_t3<<<wsQ3, 256, 0, stream>>>(Wq_l, Wk_l, Wv_l, Wt);
    gemm_mfma<5, 1><<<gQKV, 256, 0, stream>>>(Xp, Wt, bcat, nullptr, nullptr,
                                              nullptr, PL, 4096, 3072, 1024);

    attn_mfma<<<dim3(32, 8, 2), 512, 0, stream>>>(
        PL, PL + QK, PL + 2 * QK, amask, rel + (size_t)l * 1023 * 32, CTX);

    wcast_t<<<dim3(32, 32), 256, 0, stream>>>(Wo_l, Wt, 1024, 1024);
    gemm_mfma<2, 2><<<gKS, 256, 0, stream>>>(CTX, Wt, bo + l * 1024, x_in,
                                             buf_t, buf_t2, nullptr, 4096, 1024, 1024);
    ln_kernel<<<4096, 256, 0, stream>>>(buf_t, buf_t2, ln1g + l * 1024,
                                        ln1b + l * 1024, buf_h1, H1);

    wcast_t<<<dim3(4096 / 32, 1024 / 32), 256, 0, stream>>>(W1_l, Wt, 1024, 4096);
    gemm_mfma<1, 1><<<gF1, 256, 0, stream>>>(H1, Wt, b1 + l * 4096, nullptr,
                                             nullptr, nullptr, F1, 4096, 4096, 1024);
    wcast_t<<<dim3(1024 / 32, 4096 / 32), 256, 0, stream>>>(W2_l, Wt, 4096, 1024);
    gemm_mfma<2, 2><<<gKS, 256, 0, stream>>>(F1, Wt, b2 + l * 1024, buf_h1,
                                             buf_t, buf_t2, nullptr, 4096, 1024, 4096);
    ln_kernel<<<4096, 256, 0, stream>>>(buf_t, buf_t2, ln2g + l * 1024,
                                        ln2b + l * 1024, buf_x, Xp);
    x_in = buf_x;
  }

  pool_part<<<dim3(8, 8, 4), 128, 0, stream>>>(buf_x, amask, psum, pmax, pcnt);
  pool_fin<<<32, 256, 0, stream>>>(buf_x, psum, pmax, pcnt, pooled);
  pgemm_part<<<dim3(16, 16), 256, 0, stream>>>(pooled, poolW, pgpart);
  pgemm_fin<<<32, 256, 0, stream>>>(pgpart, poolb, pool_h);
  ln_kernel<<<8, 256, 0, stream>>>(pool_h, nullptr, plng, plnb, pool_h2, nullptr);
  cls_kernel<<<dim3(20, 8), 64, 0, stream>>>(pool_h2, clsW, clsb, (float*)d_out);
}

// Round 9
// 1356.109 us; speedup vs baseline: 1.0371x; 1.0371x over previous
//
#include <hip/hip_runtime.h>
#include <math.h>

typedef __attribute__((ext_vector_type(8))) _Float16 f16x8;
typedef __attribute__((ext_vector_type(4))) float f32x4;

// ---------- fp16 helpers ----------
__device__ __forceinline__ ushort f2h(float x) {
  union { _Float16 h; ushort u; } c;
  c.h = (_Float16)x;
  return c.u;
}
__device__ __forceinline__ void gl_lds16(const ushort* g, ushort* l) {
  __builtin_amdgcn_global_load_lds(
      (const __attribute__((address_space(1))) unsigned int*)g,
      (__attribute__((address_space(3))) unsigned int*)l, 16, 0, 0);
}
__device__ __forceinline__ f32x4 mfma16(f16x8 a, f16x8 b, f32x4 c) {
  return __builtin_amdgcn_mfma_f32_16x16x32_f16(a, b, c, 0, 0, 0);
}

// ---------- block-wide sum reduce (256 threads = 4 waves) ----------
__device__ __forceinline__ float block_reduce_sum(float v, float* sb) {
#pragma unroll
  for (int o = 32; o > 0; o >>= 1) v += __shfl_down(v, o, 64);
  const int t = threadIdx.x;
  if ((t & 63) == 0) sb[t >> 6] = v;
  __syncthreads();
  v = sb[0] + sb[1] + sb[2] + sb[3];
  __syncthreads();
  return v;
}

// ---------- activation cast: fp32 -> fp16 plane ----------
__global__ __launch_bounds__(256) void acast(const float* __restrict__ X,
                                             ushort* __restrict__ H, int n4) {
  const int i = blockIdx.x * 256 + threadIdx.x;
  if (i >= n4) return;
  const float4 x = ((const float4*)X)[i];
  ushort4 h;
  h.x = f2h(x.x); h.y = f2h(x.y); h.z = f2h(x.z); h.w = f2h(x.w);
  ((ushort4*)H)[i] = h;
}

// ---------- bias concat for fused QKV ----------
__global__ __launch_bounds__(256) void concat3(const float* __restrict__ a,
                                               const float* __restrict__ b,
                                               const float* __restrict__ c,
                                               float* __restrict__ o) {
  const int i = blockIdx.x * 256 + threadIdx.x;  // 0..3071
  o[i] = i < 1024 ? a[i] : (i < 2048 ? b[i - 1024] : c[i - 2048]);
}

// ---------- weight transpose+cast: W[K,N] fp32 -> T [N,K] fp16 ----------
__global__ __launch_bounds__(256) void wcast_t(const float* __restrict__ W,
                                               ushort* __restrict__ T,
                                               int K, int N) {
  __shared__ float s[32][33];
  const int tx = threadIdx.x & 31, ty = threadIdx.x >> 5;
  const int n0 = blockIdx.x * 32, k0 = blockIdx.y * 32;
#pragma unroll
  for (int i = 0; i < 4; ++i)
    s[ty + i * 8][tx] = W[(size_t)(k0 + ty + i * 8) * N + n0 + tx];
  __syncthreads();
#pragma unroll
  for (int i = 0; i < 4; ++i) {
    const int n = ty + i * 8;
    T[(size_t)(n0 + n) * K + k0 + tx] = f2h(s[tx][n]);
  }
}

// ---------- fused QKV weight transpose (3x 1024x1024) ----------
__global__ __launch_bounds__(256) void wcast_t3(const float* __restrict__ W0,
                                                const float* __restrict__ W1,
                                                const float* __restrict__ W2,
                                                ushort* __restrict__ T) {
  __shared__ float s[32][33];
  const float* W = blockIdx.z == 0 ? W0 : (blockIdx.z == 1 ? W1 : W2);
  ushort* Tp = T + (size_t)blockIdx.z * 1024 * 1024;
  const int tx = threadIdx.x & 31, ty = threadIdx.x >> 5;
  const int n0 = blockIdx.x * 32, k0 = blockIdx.y * 32;
#pragma unroll
  for (int i = 0; i < 4; ++i)
    s[ty + i * 8][tx] = W[(size_t)(k0 + ty + i * 8) * 1024 + n0 + tx];
  __syncthreads();
#pragma unroll
  for (int i = 0; i < 4; ++i) {
    const int n = ty + i * 8;
    Tp[(size_t)(n0 + n) * 1024 + k0 + tx] = f2h(s[tx][n]);
  }
}

// ---------- fp16 MFMA GEMM, 128x128 tile, BK=32, 2-buf counted-vmcnt pipe ----
// 4 waves as 2x2, 16 MFMA per wave per K-step.
// Iteration kt: issue STAGE(buf^1) first, then wait vmcnt(4) -> the 4 loads of
// buf[cur] (issued one FULL iteration earlier) are complete while the 4
// just-issued loads stay in flight. Same 32KB LDS as the r7 2-phase loop.
// EPI: 1 bias+GELU->plane O | 2 bias+res->C (KSPLIT: z0->C w/ bias+res, z1 raw->C2)
//      5 QKV fused: col<2048 -> Q/K planes [2][4096][1024]; col>=2048 ->
//        transposed V plane at O+8M: [(b*32+h)*32+d][512]
template <int EPI, int KSPLIT>
__global__ __launch_bounds__(256, 2) void gemm_mfma(
    const ushort* __restrict__ A, const ushort* __restrict__ B,
    const float* __restrict__ bias, const float* __restrict__ res,
    float* __restrict__ C, float* __restrict__ C2, ushort* __restrict__ O,
    int M, int N, int K) {
  __shared__ __align__(16) ushort sA[2][4096], sB[2][4096];
  const int t = threadIdx.x, w = t >> 6, lane = t & 63;
  const int llo = lane & 15, lhi = lane >> 4;
  const int wm = w >> 1, wn = w & 1;
  const int z = (KSPLIT > 1) ? blockIdx.z : 0;
  const int Ks = K / KSPLIT;

  // XCD-aware bijective swizzle over (x,y); all grids have nwg % 8 == 0
  const int gx = gridDim.x;
  int wg = blockIdx.y * gx + blockIdx.x;
  const int nwg = gx * gridDim.y;
  wg = (wg & 7) * (nwg >> 3) + (wg >> 3);
  const int bm = (wg / gx) * 128, bn = (wg % gx) * 128;

  const ushort* pA0 = A + (size_t)(bm + lane) * K + w * 8 + z * Ks;
  const ushort* pA1 = pA0 + (size_t)64 * K;
  const ushort* pB0 = B + (size_t)(bn + lane) * K + w * 8 + z * Ks;
  const ushort* pB1 = pB0 + (size_t)64 * K;

  auto STAGE = [&](int buf, int k0) {
    gl_lds16(pA0 + k0, &sA[buf][w * 1024]);
    gl_lds16(pA1 + k0, &sA[buf][w * 1024 + 512]);
    gl_lds16(pB0 + k0, &sB[buf][w * 1024]);
    gl_lds16(pB1 + k0, &sB[buf][w * 1024 + 512]);
  };

  f32x4 acc[4][4] = {};
  const int NT = Ks >> 5;
  STAGE(0, 0);
  int cur = 0;
  for (int kt = 0; kt < NT; ++kt) {
    if (kt + 1 < NT) {
      STAGE(cur ^ 1, (kt + 1) << 5);  // issue next tile's 4 loads
      asm volatile("s_waitcnt vmcnt(4)" ::: "memory");  // cur's loads done
    } else {
      asm volatile("s_waitcnt vmcnt(0)" ::: "memory");
    }
    asm volatile("s_barrier" ::: "memory");  // all waves' stage-cur in LDS

    f16x8 a[4], bfr[4];
#pragma unroll
    for (int f = 0; f < 4; ++f) {
      a[f] = *(const f16x8*)&sA[cur][lhi * 1024 + (wm * 64 + f * 16 + llo) * 8];
      bfr[f] = *(const f16x8*)&sB[cur][lhi * 1024 + (wn * 64 + f * 16 + llo) * 8];
    }
#pragma unroll
    for (int fm = 0; fm < 4; ++fm)
#pragma unroll
      for (int fn = 0; fn < 4; ++fn)
        acc[fm][fn] = mfma16(a[fm], bfr[fn], acc[fm][fn]);

    asm volatile("s_barrier" ::: "memory");  // reads of buf[cur] done; next
    cur ^= 1;                                // iter may overwrite it
  }

  // epilogue: C/D map col = lane&15, row = (lane>>4)*4 + r
#pragma unroll
  for (int fm = 0; fm < 4; ++fm) {
    const int row0 = bm + wm * 64 + fm * 16 + lhi * 4;
#pragma unroll
    for (int fn = 0; fn < 4; ++fn) {
      const int col = bn + wn * 64 + fn * 16 + llo;
      const float bc = bias[col];
      if (EPI == 5) {
        if (col < 2048) {
          const size_t base = (size_t)(col >> 10) * (4096 * 1024) + (col & 1023);
#pragma unroll
          for (int r = 0; r < 4; ++r)
            O[base + (size_t)(row0 + r) * 1024] = f2h(acc[fm][fn][r] + bc);
        } else {
          const int c = col - 2048;
          ushort4 vh;
#pragma unroll
          for (int r = 0; r < 4; ++r) ((ushort*)&vh)[r] = f2h(acc[fm][fn][r] + bc);
          const size_t o = (size_t)8 * 1024 * 1024 +
              ((size_t)(((row0 >> 9) * 32 + (c >> 5)) * 32 + (c & 31))) * 512 +
              (row0 & 511);
          *(ushort4*)(O + o) = vh;
        }
      } else if (EPI == 2) {
#pragma unroll
        for (int r = 0; r < 4; ++r) {
          const size_t o = (size_t)(row0 + r) * N + col;
          if (KSPLIT == 1 || z == 0)
            C[o] = acc[fm][fn][r] + bc + res[o];
          else
            C2[o] = acc[fm][fn][r];
        }
      } else {  // EPI == 1: GELU -> fp16 plane
#pragma unroll
        for (int r = 0; r < 4; ++r) {
          const size_t o = (size_t)(row0 + r) * N + col;
          float v = acc[fm][fn][r] + bc;
          v = 0.5f * v * (1.f + erff(v * 0.70710678118654752f));
          O[o] = f2h(v);
        }
      }
    }
  }
}

// ---------- fp16 MFMA flash attention per (b,h,zhalf): 512 threads ----------
// Swapped QK^T (S^T = K.Q^T); K slab [oct4][512][8]; V^T slab [koct64][32][8].
__global__ __launch_bounds__(512, 2) void attn_mfma(
    const ushort* __restrict__ Qg, const ushort* __restrict__ Kg,
    const ushort* __restrict__ Vg, const float* __restrict__ mask,
    const float* __restrict__ rel_l, ushort* __restrict__ Cg) {
  __shared__ __align__(16) ushort sK[16384], sV[16384];
  __shared__ __align__(16) ushort sP[5120];
  __shared__ float rel_s[1024];
  __shared__ float madd[512];

  const int h = blockIdx.x, b = blockIdx.y, z = blockIdx.z;
  const int t = threadIdx.x, w = t >> 6, lane = t & 63;
  const int llo = lane & 15, lhi = lane >> 4;
  const float SCALE = 0.17677669529663687f;  // 1/sqrt(32)

#pragma unroll
  for (int it = 0; it < 4; ++it) {
    const int task = t + it * 512;  // 0..2047
    const int s = task >> 2, oct = task & 3;
    const size_t g = (size_t)(b * 512 + s) * 1024 + h * 32 + oct * 8;
    *(uint4*)&sK[oct * 4096 + s * 8] = *(const uint4*)(Kg + g);
  }
#pragma unroll
  for (int it = 0; it < 4; ++it) {
    const int task = t + it * 512;  // 0..2047
    const int d = task >> 6, ko = task & 63;
    const size_t g = (size_t)((b * 32 + h) * 32 + d) * 512 + ko * 8;
    *(uint4*)&sV[ko * 256 + d * 8] = *(const uint4*)(Vg + g);
  }
  for (int i = t; i < 1023; i += 512) rel_s[i] = rel_l[(size_t)i * 32 + h];
  for (int i = t; i < 512; i += 512) madd[i] = (1.f - mask[b * 512 + i]) * -1e9f;
  __syncthreads();

  uint* wP = (uint*)(sP + w * 640 + llo * 40);
  const ushort* rP = sP + w * 640 + llo * 40;

  for (int qt = 0; qt < 2; ++qt) {
    const int q = z * 256 + w * 32 + qt * 16 + llo;
    const size_t qg = (size_t)(b * 512 + q) * 1024 + h * 32 + lhi * 8;
    const f16x8 fQ = *(const f16x8*)(Qg + qg);
    float m = -INFINITY, l = 0.f;
    f32x4 acc0 = {0.f, 0.f, 0.f, 0.f};
    f32x4 acc1 = {0.f, 0.f, 0.f, 0.f};

    for (int kt2 = 0; kt2 < 16; ++kt2) {
      float p[8];
      float tm = -INFINITY;
#pragma unroll
      for (int sub = 0; sub < 2; ++sub) {
        const int kt = kt2 * 2 + sub;
        const f16x8 fK = *(const f16x8*)&sK[lhi * 4096 + (kt * 16 + llo) * 8];
        f32x4 s4 = {0.f, 0.f, 0.f, 0.f};
        s4 = mfma16(fK, fQ, s4);
#pragma unroll
        for (int r = 0; r < 4; ++r) {
          const int k = kt * 16 + lhi * 4 + r;
          const float sv = (s4[r] + rel_s[q - k + 511]) * SCALE + madd[k];
          p[sub * 4 + r] = sv;
          tm = fmaxf(tm, sv);
        }
      }
      tm = fmaxf(tm, __shfl_xor(tm, 16));
      tm = fmaxf(tm, __shfl_xor(tm, 32));
      const float nm = fmaxf(m, tm);
      const float sc = __expf(m - nm);
      float ts = 0.f;
#pragma unroll
      for (int i = 0; i < 8; ++i) {
        p[i] = __expf(p[i] - nm);
        ts += p[i];
      }
      ts += __shfl_xor(ts, 16);
      ts += __shfl_xor(ts, 32);
      l = l * sc + ts;
      m = nm;
      acc0 *= sc;
      acc1 *= sc;
      // pack P into wave-private LDS in B-frag layout (fp16)
#pragma unroll
      for (int sub = 0; sub < 2; ++sub) {
        wP[sub * 8 + lhi * 2 + 0] =
            (uint)f2h(p[sub * 4 + 0]) | ((uint)f2h(p[sub * 4 + 1]) << 16);
        wP[sub * 8 + lhi * 2 + 1] =
            (uint)f2h(p[sub * 4 + 2]) | ((uint)f2h(p[sub * 4 + 3]) << 16);
      }
      const f16x8 fP = *(const f16x8*)(rP + lhi * 8);
      const int vb = (kt2 * 4 + lhi) * 256;
      const f16x8 fV0 = *(const f16x8*)&sV[vb + llo * 8];
      const f16x8 fV1 = *(const f16x8*)&sV[vb + (16 + llo) * 8];
      acc0 = mfma16(fV0, fP, acc0);
      acc1 = mfma16(fV1, fP, acc1);
    }

    const float invl = 1.f / l;
    const size_t ob = (size_t)(b * 512 + q) * 1024 + h * 32;
    ushort4 oh;
#pragma unroll
    for (int r = 0; r < 4; ++r) ((ushort*)&oh)[r] = f2h(acc0[r] * invl);
    *(ushort4*)(Cg + ob + lhi * 4) = oh;
#pragma unroll
    for (int r = 0; r < 4; ++r) ((ushort*)&oh)[r] = f2h(acc1[r] * invl);
    *(ushort4*)(Cg + ob + 16 + lhi * 4) = oh;
  }
}

// ---------- LayerNorm over rows of 1024 (optional 2nd addend, fp16 plane) ----
__global__ __launch_bounds__(256) void ln_kernel(
    const float* __restrict__ X, const float* __restrict__ X2,
    const float* __restrict__ g, const float* __restrict__ bt,
    float* __restrict__ out, ushort* __restrict__ O) {
  __shared__ float sb[4];
  const int row = blockIdx.x, t = threadIdx.x;
  float4 x = *(const float4*)&X[(size_t)row * 1024 + t * 4];
  if (X2) {
    const float4 y = *(const float4*)&X2[(size_t)row * 1024 + t * 4];
    x.x += y.x; x.y += y.y; x.z += y.z; x.w += y.w;
  }
  const float s = block_reduce_sum(x.x + x.y + x.z + x.w, sb);
  const float mu = s * (1.f / 1024.f);
  const float dx = x.x - mu, dy = x.y - mu, dz = x.z - mu, dw = x.w - mu;
  const float ss = block_reduce_sum(dx * dx + dy * dy + dz * dz + dw * dw, sb);
  const float rs = rsqrtf(ss * (1.f / 1024.f) + 1e-12f);
  const float4 gv = *(const float4*)&g[t * 4];
  const float4 bv = *(const float4*)&bt[t * 4];
  float4 o;
  o.x = dx * rs * gv.x + bv.x;
  o.y = dy * rs * gv.y + bv.y;
  o.z = dz * rs * gv.z + bv.z;
  o.w = dw * rs * gv.w + bv.w;
  *(float4*)&out[(size_t)row * 1024 + t * 4] = o;
  if (O) {
    ushort4 vh;
    vh.x = f2h(o.x); vh.y = f2h(o.y); vh.z = f2h(o.z); vh.w = f2h(o.w);
    *(ushort4*)&O[(size_t)row * 1024 + t * 4] = vh;
  }
}

// ---------- pooling stage 1: s-split partials ----------
__global__ __launch_bounds__(128) void pool_part(
    const float* __restrict__ X, const float* __restrict__ mask,
    float* __restrict__ psum, float* __restrict__ pmax,
    float* __restrict__ pcnt) {
  const int cb = blockIdx.x, b = blockIdx.y, sb = blockIdx.z;
  const int col = cb * 128 + threadIdx.x;
  float sum = 0.f, mx = -INFINITY, cnt = 0.f;
  for (int i = 0; i < 128; ++i) {
    const int s = sb * 128 + i;
    const float v = X[(size_t)(b * 512 + s) * 1024 + col];
    const float mk = mask[b * 512 + s];
    sum = fmaf(v, mk, sum);
    cnt += mk;
    mx = fmaxf(mx, v + (1.f - mk) * -1e9f);
  }
  psum[(size_t)(sb * 8 + b) * 1024 + col] = sum;
  pmax[(size_t)(sb * 8 + b) * 1024 + col] = mx;
  if (cb == 0 && threadIdx.x == 0) pcnt[sb * 8 + b] = cnt;
}

// ---------- pooling finalize: mean + max + first token ----------
__global__ __launch_bounds__(256) void pool_fin(
    const float* __restrict__ X, const float* __restrict__ psum,
    const float* __restrict__ pmax, const float* __restrict__ pcnt,
    float* __restrict__ pooled) {
  const int idx = blockIdx.x * 256 + threadIdx.x;  // 0..8191
  const int b = idx >> 10, col = idx & 1023;
  float s = 0.f, m = -INFINITY, c = 0.f;
#pragma unroll
  for (int sb = 0; sb < 4; ++sb) {
    s += psum[(size_t)(sb * 8 + b) * 1024 + col];
    m = fmaxf(m, pmax[(size_t)(sb * 8 + b) * 1024 + col]);
    c += pcnt[sb * 8 + b];
  }
  pooled[(size_t)b * 3072 + col] = s / c;
  pooled[(size_t)b * 3072 + 1024 + col] = m;
  pooled[(size_t)b * 3072 + 2048 + col] = X[(size_t)(b * 512) * 1024 + col];
}

// ---------- pooled GEMM stage 1: split-K partials ----------
__global__ __launch_bounds__(256) void pgemm_part(
    const float* __restrict__ P, const float* __restrict__ W,
    float* __restrict__ part) {
  __shared__ float sP[8][192];
  __shared__ float sacc[256][9];
  const int nb = blockIdx.x, kb = blockIdx.y;
  const int t = threadIdx.x;
  const int k0 = kb * 192, n0 = nb * 64;
  for (int i = t; i < 1536; i += 256)
    sP[i / 192][i % 192] = P[(size_t)(i / 192) * 3072 + k0 + i % 192];
  __syncthreads();
  const int n = t & 63, kq = t >> 6;
  float acc[8] = {};
  for (int kk = 0; kk < 48; ++kk) {
    const int k = kq * 48 + kk;
    const float wv = W[(size_t)(k0 + k) * 1024 + n0 + n];
#pragma unroll
    for (int b = 0; b < 8; ++b) acc[b] = fmaf(sP[b][k], wv, acc[b]);
  }
#pragma unroll
  for (int b = 0; b < 8; ++b) sacc[t][b] = acc[b];
  __syncthreads();
  for (int p = t; p < 512; p += 256) {
    const int b = p >> 6, nn = p & 63;
    const float v = sacc[nn][b] + sacc[64 + nn][b] + sacc[128 + nn][b] +
                    sacc[192 + nn][b];
    part[((size_t)kb * 8 + b) * 1024 + n0 + nn] = v;
  }
}

// ---------- pooled GEMM finalize ----------
__global__ __launch_bounds__(256) void pgemm_fin(
    const float* __restrict__ part, const float* __restrict__ bias,
    float* __restrict__ out) {
  const int idx = blockIdx.x * 256 + threadIdx.x;  // 0..8191
  const int b = idx >> 10, n = idx & 1023;
  float v = bias[n];
#pragma unroll
  for (int kb = 0; kb < 16; ++kb) v += part[((size_t)kb * 8 + b) * 1024 + n];
  out[(size_t)b * 1024 + n] = v;
}

// ---------- classifier: one block per (n,b), wave-reduce over K ----------
__global__ __launch_bounds__(64) void cls_kernel(
    const float* __restrict__ X, const float* __restrict__ W,
    const float* __restrict__ bias, float* __restrict__ out) {
  const int n = blockIdx.x, b = blockIdx.y, lane = threadIdx.x;
  float a = 0.f;
#pragma unroll
  for (int i = 0; i < 16; ++i) {
    const int k = lane + i * 64;
    a = fmaf(X[(size_t)b * 1024 + k], W[(size_t)k * 20 + n], a);
  }
#pragma unroll
  for (int o = 32; o > 0; o >>= 1) a += __shfl_down(a, o, 64);
  if (lane == 0) out[b * 20 + n] = a + bias[n];
}

extern "C" void kernel_launch(void* const* d_in, const int* in_sizes, int n_in,
                              void* d_out, int out_size, void* d_ws, size_t ws_size,
                              hipStream_t stream) {
  const float* hs    = (const float*)d_in[0];
  const float* amask = (const float*)d_in[1];
  const float* Wq    = (const float*)d_in[2];
  const float* bq    = (const float*)d_in[3];
  const float* Wk    = (const float*)d_in[4];
  const float* bk    = (const float*)d_in[5];
  const float* Wv    = (const float*)d_in[6];
  const float* bv    = (const float*)d_in[7];
  const float* Wo    = (const float*)d_in[8];
  const float* bo    = (const float*)d_in[9];
  const float* ln1g  = (const float*)d_in[10];
  const float* ln1b  = (const float*)d_in[11];
  const float* W1    = (const float*)d_in[12];
  const float* b1    = (const float*)d_in[13];
  const float* W2    = (const float*)d_in[14];
  const float* b2    = (const float*)d_in[15];
  const float* ln2g  = (const float*)d_in[16];
  const float* ln2b  = (const float*)d_in[17];
  const float* rel   = (const float*)d_in[18];
  const float* poolW = (const float*)d_in[19];
  const float* poolb = (const float*)d_in[20];
  const float* plng  = (const float*)d_in[21];
  const float* plnb  = (const float*)d_in[22];
  const float* clsW  = (const float*)d_in[23];
  const float* clsb  = (const float*)d_in[24];

  char* W = (char*)d_ws;
  const size_t MB = (size_t)1 << 20;
  const size_t QK = (size_t)4096 * 1024;  // Q/K plane stride (elements)
  float* buf_t  = (float*)(W + 0 * MB);    // 16MB fp32
  float* buf_t2 = (float*)(W + 16 * MB);   // 16MB fp32 (split-K partials)
  float* buf_h1 = (float*)(W + 32 * MB);   // 16MB fp32
  float* buf_x  = (float*)(W + 48 * MB);   // 16MB fp32
  ushort* PL  = (ushort*)(W + 64 * MB);    // Q(0..4M) K(4..8M) V^T(8..12M), 24MB
  ushort* CTX = (ushort*)(W + 88 * MB);    // 8MB; also next-layer X plane
  ushort* Xp  = CTX;
  ushort* H1  = (ushort*)(W + 96 * MB);    // 8MB
  ushort* F1  = (ushort*)(W + 104 * MB);   // 32MB
  ushort* Wt  = (ushort*)(W + 136 * MB);   // 6MB ([3072][1024] fp16)
  float* bcat = (float*)(W + 142 * MB);    // 12KB
  float* sm   = (float*)(W + 143 * MB);    // small-buffer region (<1.5MB)
  float* pooled  = sm;                     // 8*3072
  float* pool_h  = pooled + 8 * 3072;      // 8*1024
  float* pool_h2 = pool_h + 8 * 1024;      // 8*1024
  float* pcnt    = pool_h2 + 8 * 1024;     // 32
  float* psum    = pcnt + 64;              // 4*8*1024
  float* pmax    = psum + 4 * 8 * 1024;    // 4*8*1024
  float* pgpart  = pmax + 4 * 8 * 1024;    // 16*8*1024

  const int n4act = (4096 * 1024) / 4;
  const dim3 gQKV(3072 / 128, 32);     // 768 blocks
  const dim3 gF1(4096 / 128, 32);      // 1024 blocks
  const dim3 gKS(1024 / 128, 32, 2);   // 512 blocks (Wo, FFN2 split-K)
  const dim3 wsQ3(32, 32, 3);

  acast<<<n4act / 256, 256, 0, stream>>>(hs, Xp, n4act);

  const float* x_in = hs;
  for (int l = 0; l < 4; ++l) {
    const float* Wq_l = Wq + (size_t)l * 1024 * 1024;
    const float* Wk_l = Wk + (size_t)l * 1024 * 1024;
    const float* Wv_l = Wv + (size_t)l * 1024 * 1024;
    const float* Wo_l = Wo + (size_t)l * 1024 * 1024;
    const float* W1_l = W1 + (size_t)l * 1024 * 4096;
    const float* W2_l = W2 + (size_t)l * 4096 * 1024;

    // fused QKV
    concat3<<<12, 256, 0, stream>>>(bq + l * 1024, bk + l * 1024, bv + l * 1024, bcat);
    wcast_t3<<<wsQ3, 256, 0, stream>>>(Wq_l, Wk_l, Wv_l, Wt);
    gemm_mfma<5, 1><<<gQKV, 256, 0, stream>>>(Xp, Wt, bcat, nullptr, nullptr,
                                              nullptr, PL, 4096, 3072, 1024);

    attn_mfma<<<dim3(32, 8, 2), 512, 0, stream>>>(
        PL, PL + QK, PL + 2 * QK, amask, rel + (size_t)l * 1023 * 32, CTX);

    wcast_t<<<dim3(32, 32), 256, 0, stream>>>(Wo_l, Wt, 1024, 1024);
    gemm_mfma<2, 2><<<gKS, 256, 0, stream>>>(CTX, Wt, bo + l * 1024, x_in,
                                             buf_t, buf_t2, nullptr, 4096, 1024, 1024);
    ln_kernel<<<4096, 256, 0, stream>>>(buf_t, buf_t2, ln1g + l * 1024,
                                        ln1b + l * 1024, buf_h1, H1);

    wcast_t<<<dim3(4096 / 32, 1024 / 32), 256, 0, stream>>>(W1_l, Wt, 1024, 4096);
    gemm_mfma<1, 1><<<gF1, 256, 0, stream>>>(H1, Wt, b1 + l * 4096, nullptr,
                                             nullptr, nullptr, F1, 4096, 4096, 1024);
    wcast_t<<<dim3(1024 / 32, 4096 / 32), 256, 0, stream>>>(W2_l, Wt, 4096, 1024);
    gemm_mfma<2, 2><<<gKS, 256, 0, stream>>>(F1, Wt, b2 + l * 1024, buf_h1,
                                             buf_t, buf_t2, nullptr, 4096, 1024, 4096);
    ln_kernel<<<4096, 256, 0, stream>>>(buf_t, buf_t2, ln2g + l * 1024,
                                        ln2b + l * 1024, buf_x, Xp);
    x_in = buf_x;
  }

  pool_part<<<dim3(8, 8, 4), 128, 0, stream>>>(buf_x, amask, psum, pmax, pcnt);
  pool_fin<<<32, 256, 0, stream>>>(buf_x, psum, pmax, pcnt, pooled);
  pgemm_part<<<dim3(16, 16), 256, 0, stream>>>(pooled, poolW, pgpart);
  pgemm_fin<<<32, 256, 0, stream>>>(pgpart, poolb, pool_h);
  ln_kernel<<<8, 256, 0, stream>>>(pool_h, nullptr, plng, plnb, pool_h2, nullptr);
  cls_kernel<<<dim3(20, 8), 64, 0, stream>>>(pool_h2, clsW, clsb, (float*)d_out);
}

// Round 10
// 1350.785 us; speedup vs baseline: 1.0412x; 1.0039x over previous
//
#include <hip/hip_runtime.h>
#include <math.h>

typedef __attribute__((ext_vector_type(8))) _Float16 f16x8;
typedef __attribute__((ext_vector_type(4))) float f32x4;

// ---------- fp16 helpers ----------
__device__ __forceinline__ ushort f2h(float x) {
  union { _Float16 h; ushort u; } c;
  c.h = (_Float16)x;
  return c.u;
}
__device__ __forceinline__ void gl_lds16(const ushort* g, ushort* l) {
  __builtin_amdgcn_global_load_lds(
      (const __attribute__((address_space(1))) unsigned int*)g,
      (__attribute__((address_space(3))) unsigned int*)l, 16, 0, 0);
}
__device__ __forceinline__ f32x4 mfma16(f16x8 a, f16x8 b, f32x4 c) {
  return __builtin_amdgcn_mfma_f32_16x16x32_f16(a, b, c, 0, 0, 0);
}

// ---------- block-wide sum reduce (256 threads = 4 waves) ----------
__device__ __forceinline__ float block_reduce_sum(float v, float* sb) {
#pragma unroll
  for (int o = 32; o > 0; o >>= 1) v += __shfl_down(v, o, 64);
  const int t = threadIdx.x;
  if ((t & 63) == 0) sb[t >> 6] = v;
  __syncthreads();
  v = sb[0] + sb[1] + sb[2] + sb[3];
  __syncthreads();
  return v;
}

// ---------- activation cast: fp32 -> fp16 plane ----------
__global__ __launch_bounds__(256) void acast(const float* __restrict__ X,
                                             ushort* __restrict__ H, int n4) {
  const int i = blockIdx.x * 256 + threadIdx.x;
  if (i >= n4) return;
  const float4 x = ((const float4*)X)[i];
  ushort4 h;
  h.x = f2h(x.x); h.y = f2h(x.y); h.z = f2h(x.z); h.w = f2h(x.w);
  ((ushort4*)H)[i] = h;
}

// ---------- bias concat for fused QKV ----------
__global__ __launch_bounds__(256) void concat3(const float* __restrict__ a,
                                               const float* __restrict__ b,
                                               const float* __restrict__ c,
                                               float* __restrict__ o) {
  const int i = blockIdx.x * 256 + threadIdx.x;  // 0..3071
  o[i] = i < 1024 ? a[i] : (i < 2048 ? b[i - 1024] : c[i - 2048]);
}

// ---------- weight transpose+cast: W[K,N] fp32 -> T [N,K] fp16 ----------
__global__ __launch_bounds__(256) void wcast_t(const float* __restrict__ W,
                                               ushort* __restrict__ T,
                                               int K, int N) {
  __shared__ float s[32][33];
  const int tx = threadIdx.x & 31, ty = threadIdx.x >> 5;
  const int n0 = blockIdx.x * 32, k0 = blockIdx.y * 32;
#pragma unroll
  for (int i = 0; i < 4; ++i)
    s[ty + i * 8][tx] = W[(size_t)(k0 + ty + i * 8) * N + n0 + tx];
  __syncthreads();
#pragma unroll
  for (int i = 0; i < 4; ++i) {
    const int n = ty + i * 8;
    T[(size_t)(n0 + n) * K + k0 + tx] = f2h(s[tx][n]);
  }
}

// ---------- fused QKV weight transpose (3x 1024x1024) ----------
__global__ __launch_bounds__(256) void wcast_t3(const float* __restrict__ W0,
                                                const float* __restrict__ W1,
                                                const float* __restrict__ W2,
                                                ushort* __restrict__ T) {
  __shared__ float s[32][33];
  const float* W = blockIdx.z == 0 ? W0 : (blockIdx.z == 1 ? W1 : W2);
  ushort* Tp = T + (size_t)blockIdx.z * 1024 * 1024;
  const int tx = threadIdx.x & 31, ty = threadIdx.x >> 5;
  const int n0 = blockIdx.x * 32, k0 = blockIdx.y * 32;
#pragma unroll
  for (int i = 0; i < 4; ++i)
    s[ty + i * 8][tx] = W[(size_t)(k0 + ty + i * 8) * 1024 + n0 + tx];
  __syncthreads();
#pragma unroll
  for (int i = 0; i < 4; ++i) {
    const int n = ty + i * 8;
    Tp[(size_t)(n0 + n) * 1024 + k0 + tx] = f2h(s[tx][n]);
  }
}

// ---------- fp16 MFMA GEMM, 256x256 tile, BK=32, 512 thr, 2-phase dbuf ------
// 8 waves as 2M x 4N; per-wave 128x64 output = 8x4 fragments, 32 MFMA/K-step.
// LDS slab per oct: [ko 4][256 rows][8] -> conflict-free b128 frag reads.
// EPI: 1 bias+GELU->plane O | 5 QKV fused (col<2048 -> Q/K planes; else V^T)
template <int EPI>
__global__ __launch_bounds__(512, 2) void gemm256(
    const ushort* __restrict__ A, const ushort* __restrict__ B,
    const float* __restrict__ bias, float* __restrict__ C,
    ushort* __restrict__ O, int M, int N, int K) {
  __shared__ __align__(16) ushort sA[2][8192], sB[2][8192];
  const int t = threadIdx.x, w = t >> 6, lane = t & 63;
  const int llo = lane & 15, lhi = lane >> 4;
  const int wm = w >> 2, wn = w & 3;   // compute role
  const int rb = w >> 2, ko = w & 3;   // staging role

  // XCD-aware bijective swizzle (grids: 256, 192 -> nwg % 8 == 0)
  const int gx = gridDim.x;
  int wg = blockIdx.y * gx + blockIdx.x;
  const int nwg = gx * gridDim.y;
  wg = (wg & 7) * (nwg >> 3) + (wg >> 3);
  const int bm = (wg / gx) * 256, bn = (wg % gx) * 256;

  const ushort* pA0 = A + (size_t)(bm + rb * 128 + lane) * K + ko * 8;
  const ushort* pA1 = pA0 + (size_t)64 * K;
  const ushort* pB0 = B + (size_t)(bn + rb * 128 + lane) * K + ko * 8;
  const ushort* pB1 = pB0 + (size_t)64 * K;

  auto STAGE = [&](int buf, int k0) {
    gl_lds16(pA0 + k0, &sA[buf][ko * 2048 + rb * 1024]);
    gl_lds16(pA1 + k0, &sA[buf][ko * 2048 + rb * 1024 + 512]);
    gl_lds16(pB0 + k0, &sB[buf][ko * 2048 + rb * 1024]);
    gl_lds16(pB1 + k0, &sB[buf][ko * 2048 + rb * 1024 + 512]);
  };

  f32x4 acc[8][4] = {};
  const int NT = K >> 5;
  STAGE(0, 0);
  __syncthreads();
  int cur = 0;
  for (int kt = 0; kt < NT; ++kt) {
    if (kt + 1 < NT) STAGE(cur ^ 1, (kt + 1) << 5);  // prefetch next tile
    f16x8 a[8], bfr[4];
#pragma unroll
    for (int f = 0; f < 8; ++f)
      a[f] = *(const f16x8*)&sA[cur][lhi * 2048 + (wm * 128 + f * 16 + llo) * 8];
#pragma unroll
    for (int f = 0; f < 4; ++f)
      bfr[f] = *(const f16x8*)&sB[cur][lhi * 2048 + (wn * 64 + f * 16 + llo) * 8];
#pragma unroll
    for (int fm = 0; fm < 8; ++fm)
#pragma unroll
      for (int fn = 0; fn < 4; ++fn)
        acc[fm][fn] = mfma16(a[fm], bfr[fn], acc[fm][fn]);
    __syncthreads();  // vmcnt drain (prefetch was issued BEFORE compute)
    cur ^= 1;
  }

  // epilogue: C/D map col = lane&15, row = (lane>>4)*4 + r
#pragma unroll
  for (int fm = 0; fm < 8; ++fm) {
    const int row0 = bm + wm * 128 + fm * 16 + lhi * 4;
#pragma unroll
    for (int fn = 0; fn < 4; ++fn) {
      const int col = bn + wn * 64 + fn * 16 + llo;
      const float bc = bias[col];
      if (EPI == 5) {
        if (col < 2048) {
          const size_t base = (size_t)(col >> 10) * (4096 * 1024) + (col & 1023);
#pragma unroll
          for (int r = 0; r < 4; ++r)
            O[base + (size_t)(row0 + r) * 1024] = f2h(acc[fm][fn][r] + bc);
        } else {
          const int c = col - 2048;
          ushort4 vh;
#pragma unroll
          for (int r = 0; r < 4; ++r) ((ushort*)&vh)[r] = f2h(acc[fm][fn][r] + bc);
          const size_t o = (size_t)8 * 1024 * 1024 +
              ((size_t)(((row0 >> 9) * 32 + (c >> 5)) * 32 + (c & 31))) * 512 +
              (row0 & 511);
          *(ushort4*)(O + o) = vh;
        }
      } else {  // EPI == 1: GELU -> fp16 plane
#pragma unroll
        for (int r = 0; r < 4; ++r) {
          const size_t o = (size_t)(row0 + r) * N + col;
          float v = acc[fm][fn][r] + bc;
          v = 0.5f * v * (1.f + erff(v * 0.70710678118654752f));
          O[o] = f2h(v);
        }
      }
    }
  }
}

// ---------- fp16 MFMA GEMM, 128x128 tile, BK=32, dbuf 2-phase (r7 form) -----
// Used for Wo / FFN2 (N=1024 shapes) with split-K over blockIdx.z.
// EPI: 2 bias+res->C (KSPLIT: z0->C w/ bias+res, z1 raw->C2)
template <int EPI, int KSPLIT>
__global__ __launch_bounds__(256, 2) void gemm_mfma(
    const ushort* __restrict__ A, const ushort* __restrict__ B,
    const float* __restrict__ bias, const float* __restrict__ res,
    float* __restrict__ C, float* __restrict__ C2, ushort* __restrict__ O,
    int M, int N, int K) {
  __shared__ __align__(16) ushort sA[2][4096], sB[2][4096];
  const int t = threadIdx.x, w = t >> 6, lane = t & 63;
  const int llo = lane & 15, lhi = lane >> 4;
  const int wm = w >> 1, wn = w & 1;
  const int z = (KSPLIT > 1) ? blockIdx.z : 0;
  const int Ks = K / KSPLIT;

  const int gx = gridDim.x;
  int wg = blockIdx.y * gx + blockIdx.x;
  const int nwg = gx * gridDim.y;
  wg = (wg & 7) * (nwg >> 3) + (wg >> 3);
  const int bm = (wg / gx) * 128, bn = (wg % gx) * 128;

  const ushort* pA0 = A + (size_t)(bm + lane) * K + w * 8 + z * Ks;
  const ushort* pA1 = pA0 + (size_t)64 * K;
  const ushort* pB0 = B + (size_t)(bn + lane) * K + w * 8 + z * Ks;
  const ushort* pB1 = pB0 + (size_t)64 * K;

  auto STAGE = [&](int buf, int k0) {
    gl_lds16(pA0 + k0, &sA[buf][w * 1024]);
    gl_lds16(pA1 + k0, &sA[buf][w * 1024 + 512]);
    gl_lds16(pB0 + k0, &sB[buf][w * 1024]);
    gl_lds16(pB1 + k0, &sB[buf][w * 1024 + 512]);
  };

  f32x4 acc[4][4] = {};
  const int NT = Ks >> 5;
  STAGE(0, 0);
  __syncthreads();
  int cur = 0;
  for (int kt = 0; kt < NT; ++kt) {
    if (kt + 1 < NT) STAGE(cur ^ 1, (kt + 1) << 5);
    f16x8 a[4], bfr[4];
#pragma unroll
    for (int f = 0; f < 4; ++f) {
      a[f] = *(const f16x8*)&sA[cur][lhi * 1024 + (wm * 64 + f * 16 + llo) * 8];
      bfr[f] = *(const f16x8*)&sB[cur][lhi * 1024 + (wn * 64 + f * 16 + llo) * 8];
    }
#pragma unroll
    for (int fm = 0; fm < 4; ++fm)
#pragma unroll
      for (int fn = 0; fn < 4; ++fn)
        acc[fm][fn] = mfma16(a[fm], bfr[fn], acc[fm][fn]);
    __syncthreads();
    cur ^= 1;
  }

#pragma unroll
  for (int fm = 0; fm < 4; ++fm) {
    const int row0 = bm + wm * 64 + fm * 16 + lhi * 4;
#pragma unroll
    for (int fn = 0; fn < 4; ++fn) {
      const int col = bn + wn * 64 + fn * 16 + llo;
      const float bc = bias[col];
#pragma unroll
      for (int r = 0; r < 4; ++r) {
        const size_t o = (size_t)(row0 + r) * N + col;
        if (KSPLIT == 1 || z == 0)
          C[o] = acc[fm][fn][r] + bc + res[o];
        else
          C2[o] = acc[fm][fn][r];
      }
    }
  }
}

// ---------- fp16 MFMA flash attention per (b,h,zhalf): 512 threads ----------
// Swapped QK^T (S^T = K.Q^T); K slab [oct4][512][8]; V^T slab [koct64][32][8].
__global__ __launch_bounds__(512, 2) void attn_mfma(
    const ushort* __restrict__ Qg, const ushort* __restrict__ Kg,
    const ushort* __restrict__ Vg, const float* __restrict__ mask,
    const float* __restrict__ rel_l, ushort* __restrict__ Cg) {
  __shared__ __align__(16) ushort sK[16384], sV[16384];
  __shared__ __align__(16) ushort sP[5120];
  __shared__ float rel_s[1024];
  __shared__ float madd[512];

  const int h = blockIdx.x, b = blockIdx.y, z = blockIdx.z;
  const int t = threadIdx.x, w = t >> 6, lane = t & 63;
  const int llo = lane & 15, lhi = lane >> 4;
  const float SCALE = 0.17677669529663687f;  // 1/sqrt(32)

#pragma unroll
  for (int it = 0; it < 4; ++it) {
    const int task = t + it * 512;  // 0..2047
    const int s = task >> 2, oct = task & 3;
    const size_t g = (size_t)(b * 512 + s) * 1024 + h * 32 + oct * 8;
    *(uint4*)&sK[oct * 4096 + s * 8] = *(const uint4*)(Kg + g);
  }
#pragma unroll
  for (int it = 0; it < 4; ++it) {
    const int task = t + it * 512;  // 0..2047
    const int d = task >> 6, ko = task & 63;
    const size_t g = (size_t)((b * 32 + h) * 32 + d) * 512 + ko * 8;
    *(uint4*)&sV[ko * 256 + d * 8] = *(const uint4*)(Vg + g);
  }
  for (int i = t; i < 1023; i += 512) rel_s[i] = rel_l[(size_t)i * 32 + h];
  for (int i = t; i < 512; i += 512) madd[i] = (1.f - mask[b * 512 + i]) * -1e9f;
  __syncthreads();

  uint* wP = (uint*)(sP + w * 640 + llo * 40);
  const ushort* rP = sP + w * 640 + llo * 40;

  for (int qt = 0; qt < 2; ++qt) {
    const int q = z * 256 + w * 32 + qt * 16 + llo;
    const size_t qg = (size_t)(b * 512 + q) * 1024 + h * 32 + lhi * 8;
    const f16x8 fQ = *(const f16x8*)(Qg + qg);
    float m = -INFINITY, l = 0.f;
    f32x4 acc0 = {0.f, 0.f, 0.f, 0.f};
    f32x4 acc1 = {0.f, 0.f, 0.f, 0.f};

    for (int kt2 = 0; kt2 < 16; ++kt2) {
      float p[8];
      float tm = -INFINITY;
#pragma unroll
      for (int sub = 0; sub < 2; ++sub) {
        const int kt = kt2 * 2 + sub;
        const f16x8 fK = *(const f16x8*)&sK[lhi * 4096 + (kt * 16 + llo) * 8];
        f32x4 s4 = {0.f, 0.f, 0.f, 0.f};
        s4 = mfma16(fK, fQ, s4);
#pragma unroll
        for (int r = 0; r < 4; ++r) {
          const int k = kt * 16 + lhi * 4 + r;
          const float sv = (s4[r] + rel_s[q - k + 511]) * SCALE + madd[k];
          p[sub * 4 + r] = sv;
          tm = fmaxf(tm, sv);
        }
      }
      tm = fmaxf(tm, __shfl_xor(tm, 16));
      tm = fmaxf(tm, __shfl_xor(tm, 32));
      const float nm = fmaxf(m, tm);
      const float sc = __expf(m - nm);
      float ts = 0.f;
#pragma unroll
      for (int i = 0; i < 8; ++i) {
        p[i] = __expf(p[i] - nm);
        ts += p[i];
      }
      ts += __shfl_xor(ts, 16);
      ts += __shfl_xor(ts, 32);
      l = l * sc + ts;
      m = nm;
      acc0 *= sc;
      acc1 *= sc;
      // pack P into wave-private LDS in B-frag layout (fp16)
#pragma unroll
      for (int sub = 0; sub < 2; ++sub) {
        wP[sub * 8 + lhi * 2 + 0] =
            (uint)f2h(p[sub * 4 + 0]) | ((uint)f2h(p[sub * 4 + 1]) << 16);
        wP[sub * 8 + lhi * 2 + 1] =
            (uint)f2h(p[sub * 4 + 2]) | ((uint)f2h(p[sub * 4 + 3]) << 16);
      }
      const f16x8 fP = *(const f16x8*)(rP + lhi * 8);
      const int vb = (kt2 * 4 + lhi) * 256;
      const f16x8 fV0 = *(const f16x8*)&sV[vb + llo * 8];
      const f16x8 fV1 = *(const f16x8*)&sV[vb + (16 + llo) * 8];
      acc0 = mfma16(fV0, fP, acc0);
      acc1 = mfma16(fV1, fP, acc1);
    }

    const float invl = 1.f / l;
    const size_t ob = (size_t)(b * 512 + q) * 1024 + h * 32;
    ushort4 oh;
#pragma unroll
    for (int r = 0; r < 4; ++r) ((ushort*)&oh)[r] = f2h(acc0[r] * invl);
    *(ushort4*)(Cg + ob + lhi * 4) = oh;
#pragma unroll
    for (int r = 0; r < 4; ++r) ((ushort*)&oh)[r] = f2h(acc1[r] * invl);
    *(ushort4*)(Cg + ob + 16 + lhi * 4) = oh;
  }
}

// ---------- LayerNorm over rows of 1024 (optional 2nd addend, fp16 plane) ----
__global__ __launch_bounds__(256) void ln_kernel(
    const float* __restrict__ X, const float* __restrict__ X2,
    const float* __restrict__ g, const float* __restrict__ bt,
    float* __restrict__ out, ushort* __restrict__ O) {
  __shared__ float sb[4];
  const int row = blockIdx.x, t = threadIdx.x;
  float4 x = *(const float4*)&X[(size_t)row * 1024 + t * 4];
  if (X2) {
    const float4 y = *(const float4*)&X2[(size_t)row * 1024 + t * 4];
    x.x += y.x; x.y += y.y; x.z += y.z; x.w += y.w;
  }
  const float s = block_reduce_sum(x.x + x.y + x.z + x.w, sb);
  const float mu = s * (1.f / 1024.f);
  const float dx = x.x - mu, dy = x.y - mu, dz = x.z - mu, dw = x.w - mu;
  const float ss = block_reduce_sum(dx * dx + dy * dy + dz * dz + dw * dw, sb);
  const float rs = rsqrtf(ss * (1.f / 1024.f) + 1e-12f);
  const float4 gv = *(const float4*)&g[t * 4];
  const float4 bv = *(const float4*)&bt[t * 4];
  float4 o;
  o.x = dx * rs * gv.x + bv.x;
  o.y = dy * rs * gv.y + bv.y;
  o.z = dz * rs * gv.z + bv.z;
  o.w = dw * rs * gv.w + bv.w;
  *(float4*)&out[(size_t)row * 1024 + t * 4] = o;
  if (O) {
    ushort4 vh;
    vh.x = f2h(o.x); vh.y = f2h(o.y); vh.z = f2h(o.z); vh.w = f2h(o.w);
    *(ushort4*)&O[(size_t)row * 1024 + t * 4] = vh;
  }
}

// ---------- pooling stage 1: s-split partials ----------
__global__ __launch_bounds__(128) void pool_part(
    const float* __restrict__ X, const float* __restrict__ mask,
    float* __restrict__ psum, float* __restrict__ pmax,
    float* __restrict__ pcnt) {
  const int cb = blockIdx.x, b = blockIdx.y, sb = blockIdx.z;
  const int col = cb * 128 + threadIdx.x;
  float sum = 0.f, mx = -INFINITY, cnt = 0.f;
  for (int i = 0; i < 128; ++i) {
    const int s = sb * 128 + i;
    const float v = X[(size_t)(b * 512 + s) * 1024 + col];
    const float mk = mask[b * 512 + s];
    sum = fmaf(v, mk, sum);
    cnt += mk;
    mx = fmaxf(mx, v + (1.f - mk) * -1e9f);
  }
  psum[(size_t)(sb * 8 + b) * 1024 + col] = sum;
  pmax[(size_t)(sb * 8 + b) * 1024 + col] = mx;
  if (cb == 0 && threadIdx.x == 0) pcnt[sb * 8 + b] = cnt;
}

// ---------- pooling finalize: mean + max + first token ----------
__global__ __launch_bounds__(256) void pool_fin(
    const float* __restrict__ X, const float* __restrict__ psum,
    const float* __restrict__ pmax, const float* __restrict__ pcnt,
    float* __restrict__ pooled) {
  const int idx = blockIdx.x * 256 + threadIdx.x;  // 0..8191
  const int b = idx >> 10, col = idx & 1023;
  float s = 0.f, m = -INFINITY, c = 0.f;
#pragma unroll
  for (int sb = 0; sb < 4; ++sb) {
    s += psum[(size_t)(sb * 8 + b) * 1024 + col];
    m = fmaxf(m, pmax[(size_t)(sb * 8 + b) * 1024 + col]);
    c += pcnt[sb * 8 + b];
  }
  pooled[(size_t)b * 3072 + col] = s / c;
  pooled[(size_t)b * 3072 + 1024 + col] = m;
  pooled[(size_t)b * 3072 + 2048 + col] = X[(size_t)(b * 512) * 1024 + col];
}

// ---------- pooled GEMM stage 1: split-K partials ----------
__global__ __launch_bounds__(256) void pgemm_part(
    const float* __restrict__ P, const float* __restrict__ W,
    float* __restrict__ part) {
  __shared__ float sP[8][192];
  __shared__ float sacc[256][9];
  const int nb = blockIdx.x, kb = blockIdx.y;
  const int t = threadIdx.x;
  const int k0 = kb * 192, n0 = nb * 64;
  for (int i = t; i < 1536; i += 256)
    sP[i / 192][i % 192] = P[(size_t)(i / 192) * 3072 + k0 + i % 192];
  __syncthreads();
  const int n = t & 63, kq = t >> 6;
  float acc[8] = {};
  for (int kk = 0; kk < 48; ++kk) {
    const int k = kq * 48 + kk;
    const float wv = W[(size_t)(k0 + k) * 1024 + n0 + n];
#pragma unroll
    for (int b = 0; b < 8; ++b) acc[b] = fmaf(sP[b][k], wv, acc[b]);
  }
#pragma unroll
  for (int b = 0; b < 8; ++b) sacc[t][b] = acc[b];
  __syncthreads();
  for (int p = t; p < 512; p += 256) {
    const int b = p >> 6, nn = p & 63;
    const float v = sacc[nn][b] + sacc[64 + nn][b] + sacc[128 + nn][b] +
                    sacc[192 + nn][b];
    part[((size_t)kb * 8 + b) * 1024 + n0 + nn] = v;
  }
}

// ---------- pooled GEMM finalize ----------
__global__ __launch_bounds__(256) void pgemm_fin(
    const float* __restrict__ part, const float* __restrict__ bias,
    float* __restrict__ out) {
  const int idx = blockIdx.x * 256 + threadIdx.x;  // 0..8191
  const int b = idx >> 10, n = idx & 1023;
  float v = bias[n];
#pragma unroll
  for (int kb = 0; kb < 16; ++kb) v += part[((size_t)kb * 8 + b) * 1024 + n];
  out[(size_t)b * 1024 + n] = v;
}

// ---------- classifier: one block per (n,b), wave-reduce over K ----------
__global__ __launch_bounds__(64) void cls_kernel(
    const float* __restrict__ X, const float* __restrict__ W,
    const float* __restrict__ bias, float* __restrict__ out) {
  const int n = blockIdx.x, b = blockIdx.y, lane = threadIdx.x;
  float a = 0.f;
#pragma unroll
  for (int i = 0; i < 16; ++i) {
    const int k = lane + i * 64;
    a = fmaf(X[(size_t)b * 1024 + k], W[(size_t)k * 20 + n], a);
  }
#pragma unroll
  for (int o = 32; o > 0; o >>= 1) a += __shfl_down(a, o, 64);
  if (lane == 0) out[b * 20 + n] = a + bias[n];
}

extern "C" void kernel_launch(void* const* d_in, const int* in_sizes, int n_in,
                              void* d_out, int out_size, void* d_ws, size_t ws_size,
                              hipStream_t stream) {
  const float* hs    = (const float*)d_in[0];
  const float* amask = (const float*)d_in[1];
  const float* Wq    = (const float*)d_in[2];
  const float* bq    = (const float*)d_in[3];
  const float* Wk    = (const float*)d_in[4];
  const float* bk    = (const float*)d_in[5];
  const float* Wv    = (const float*)d_in[6];
  const float* bv    = (const float*)d_in[7];
  const float* Wo    = (const float*)d_in[8];
  const float* bo    = (const float*)d_in[9];
  const float* ln1g  = (const float*)d_in[10];
  const float* ln1b  = (const float*)d_in[11];
  const float* W1    = (const float*)d_in[12];
  const float* b1    = (const float*)d_in[13];
  const float* W2    = (const float*)d_in[14];
  const float* b2    = (const float*)d_in[15];
  const float* ln2g  = (const float*)d_in[16];
  const float* ln2b  = (const float*)d_in[17];
  const float* rel   = (const float*)d_in[18];
  const float* poolW = (const float*)d_in[19];
  const float* poolb = (const float*)d_in[20];
  const float* plng  = (const float*)d_in[21];
  const float* plnb  = (const float*)d_in[22];
  const float* clsW  = (const float*)d_in[23];
  const float* clsb  = (const float*)d_in[24];

  char* W = (char*)d_ws;
  const size_t MB = (size_t)1 << 20;
  const size_t QK = (size_t)4096 * 1024;  // Q/K plane stride (elements)
  float* buf_t  = (float*)(W + 0 * MB);    // 16MB fp32
  float* buf_t2 = (float*)(W + 16 * MB);   // 16MB fp32 (split-K partials)
  float* buf_h1 = (float*)(W + 32 * MB);   // 16MB fp32
  float* buf_x  = (float*)(W + 48 * MB);   // 16MB fp32
  ushort* PL  = (ushort*)(W + 64 * MB);    // Q(0..4M) K(4..8M) V^T(8..12M), 24MB
  ushort* CTX = (ushort*)(W + 88 * MB);    // 8MB; also next-layer X plane
  ushort* Xp  = CTX;
  ushort* H1  = (ushort*)(W + 96 * MB);    // 8MB
  ushort* F1  = (ushort*)(W + 104 * MB);   // 32MB
  ushort* Wt  = (ushort*)(W + 136 * MB);   // 6MB ([3072][1024] fp16)
  float* bcat = (float*)(W + 142 * MB);    // 12KB
  float* sm   = (float*)(W + 143 * MB);    // small-buffer region (<1.5MB)
  float* pooled  = sm;                     // 8*3072
  float* pool_h  = pooled + 8 * 3072;      // 8*1024
  float* pool_h2 = pool_h + 8 * 1024;      // 8*1024
  float* pcnt    = pool_h2 + 8 * 1024;     // 32
  float* psum    = pcnt + 64;              // 4*8*1024
  float* pmax    = psum + 4 * 8 * 1024;    // 4*8*1024
  float* pgpart  = pmax + 4 * 8 * 1024;    // 16*8*1024

  const int n4act = (4096 * 1024) / 4;
  const dim3 gQKV(3072 / 256, 4096 / 256);  // 12 x 16 = 192 blocks, 512 thr
  const dim3 gF1(4096 / 256, 4096 / 256);   // 16 x 16 = 256 blocks, 512 thr
  const dim3 gKS(1024 / 128, 32, 2);        // 512 blocks (Wo, FFN2 split-K)
  const dim3 wsQ3(32, 32, 3);

  acast<<<n4act / 256, 256, 0, stream>>>(hs, Xp, n4act);

  const float* x_in = hs;
  for (int l = 0; l < 4; ++l) {
    const float* Wq_l = Wq + (size_t)l * 1024 * 1024;
    const float* Wk_l = Wk + (size_t)l * 1024 * 1024;
    const float* Wv_l = Wv + (size_t)l * 1024 * 1024;
    const float* Wo_l = Wo + (size_t)l * 1024 * 1024;
    const float* W1_l = W1 + (size_t)l * 1024 * 4096;
    const float* W2_l = W2 + (size_t)l * 4096 * 1024;

    // fused QKV (256^2 tile)
    concat3<<<12, 256, 0, stream>>>(bq + l * 1024, bk + l * 1024, bv + l * 1024, bcat);
    wcast_t3<<<wsQ3, 256, 0, stream>>>(Wq_l, Wk_l, Wv_l, Wt);
    gemm256<5><<<gQKV, 512, 0, stream>>>(Xp, Wt, bcat, nullptr, PL,
                                         4096, 3072, 1024);

    attn_mfma<<<dim3(32, 8, 2), 512, 0, stream>>>(
        PL, PL + QK, PL + 2 * QK, amask, rel + (size_t)l * 1023 * 32, CTX);

    wcast_t<<<dim3(32, 32), 256, 0, stream>>>(Wo_l, Wt, 1024, 1024);
    gemm_mfma<2, 2><<<gKS, 256, 0, stream>>>(CTX, Wt, bo + l * 1024, x_in,
                                             buf_t, buf_t2, nullptr, 4096, 1024, 1024);
    ln_kernel<<<4096, 256, 0, stream>>>(buf_t, buf_t2, ln1g + l * 1024,
                                        ln1b + l * 1024, buf_h1, H1);

    // FFN1 (256^2 tile)
    wcast_t<<<dim3(4096 / 32, 1024 / 32), 256, 0, stream>>>(W1_l, Wt, 1024, 4096);
    gemm256<1><<<gF1, 512, 0, stream>>>(H1, Wt, b1 + l * 4096, nullptr, F1,
                                        4096, 4096, 1024);
    wcast_t<<<dim3(1024 / 32, 4096 / 32), 256, 0, stream>>>(W2_l, Wt, 4096, 1024);
    gemm_mfma<2, 2><<<gKS, 256, 0, stream>>>(F1, Wt, b2 + l * 1024, buf_h1,
                                             buf_t, buf_t2, nullptr, 4096, 1024, 4096);
    ln_kernel<<<4096, 256, 0, stream>>>(buf_t, buf_t2, ln2g + l * 1024,
                                        ln2b + l * 1024, buf_x, Xp);
    x_in = buf_x;
  }

  pool_part<<<dim3(8, 8, 4), 128, 0, stream>>>(buf_x, amask, psum, pmax, pcnt);
  pool_fin<<<32, 256, 0, stream>>>(buf_x, psum, pmax, pcnt, pooled);
  pgemm_part<<<dim3(16, 16), 256, 0, stream>>>(pooled, poolW, pgpart);
  pgemm_fin<<<32, 256, 0, stream>>>(pgpart, poolb, pool_h);
  ln_kernel<<<8, 256, 0, stream>>>(pool_h, nullptr, plng, plnb, pool_h2, nullptr);
  cls_kernel<<<dim3(20, 8), 64, 0, stream>>>(pool_h2, clsW, clsb, (float*)d_out);
}

// Round 11
// 1340.158 us; speedup vs baseline: 1.0494x; 1.0079x over previous
//
#include <hip/hip_runtime.h>
#include <math.h>

typedef __attribute__((ext_vector_type(8))) _Float16 f16x8;
typedef __attribute__((ext_vector_type(4))) float f32x4;

// ---------- fp16 helpers ----------
__device__ __forceinline__ ushort f2h(float x) {
  union { _Float16 h; ushort u; } c;
  c.h = (_Float16)x;
  return c.u;
}
__device__ __forceinline__ void gl_lds16(const ushort* g, ushort* l) {
  __builtin_amdgcn_global_load_lds(
      (const __attribute__((address_space(1))) unsigned int*)g,
      (__attribute__((address_space(3))) unsigned int*)l, 16, 0, 0);
}
__device__ __forceinline__ f32x4 mfma16(f16x8 a, f16x8 b, f32x4 c) {
  return __builtin_amdgcn_mfma_f32_16x16x32_f16(a, b, c, 0, 0, 0);
}

// ---------- block-wide sum reduce (256 threads = 4 waves) ----------
__device__ __forceinline__ float block_reduce_sum(float v, float* sb) {
#pragma unroll
  for (int o = 32; o > 0; o >>= 1) v += __shfl_down(v, o, 64);
  const int t = threadIdx.x;
  if ((t & 63) == 0) sb[t >> 6] = v;
  __syncthreads();
  v = sb[0] + sb[1] + sb[2] + sb[3];
  __syncthreads();
  return v;
}

// ---------- activation cast: fp32 -> fp16 plane ----------
__global__ __launch_bounds__(256) void acast(const float* __restrict__ X,
                                             ushort* __restrict__ H, int n4) {
  const int i = blockIdx.x * 256 + threadIdx.x;
  if (i >= n4) return;
  const float4 x = ((const float4*)X)[i];
  ushort4 h;
  h.x = f2h(x.x); h.y = f2h(x.y); h.z = f2h(x.z); h.w = f2h(x.w);
  ((ushort4*)H)[i] = h;
}

// ---------- bias concat for fused QKV ----------
__global__ __launch_bounds__(256) void concat3(const float* __restrict__ a,
                                               const float* __restrict__ b,
                                               const float* __restrict__ c,
                                               float* __restrict__ o) {
  const int i = blockIdx.x * 256 + threadIdx.x;  // 0..3071
  o[i] = i < 1024 ? a[i] : (i < 2048 ? b[i - 1024] : c[i - 2048]);
}

// ---------- weight transpose+cast: W[K,N] fp32 -> T [N,K] fp16 ----------
__global__ __launch_bounds__(256) void wcast_t(const float* __restrict__ W,
                                               ushort* __restrict__ T,
                                               int K, int N) {
  __shared__ float s[32][33];
  const int tx = threadIdx.x & 31, ty = threadIdx.x >> 5;
  const int n0 = blockIdx.x * 32, k0 = blockIdx.y * 32;
#pragma unroll
  for (int i = 0; i < 4; ++i)
    s[ty + i * 8][tx] = W[(size_t)(k0 + ty + i * 8) * N + n0 + tx];
  __syncthreads();
#pragma unroll
  for (int i = 0; i < 4; ++i) {
    const int n = ty + i * 8;
    T[(size_t)(n0 + n) * K + k0 + tx] = f2h(s[tx][n]);
  }
}

// ---------- fused QKV weight transpose (3x 1024x1024) ----------
__global__ __launch_bounds__(256) void wcast_t3(const float* __restrict__ W0,
                                                const float* __restrict__ W1,
                                                const float* __restrict__ W2,
                                                ushort* __restrict__ T) {
  __shared__ float s[32][33];
  const float* W = blockIdx.z == 0 ? W0 : (blockIdx.z == 1 ? W1 : W2);
  ushort* Tp = T + (size_t)blockIdx.z * 1024 * 1024;
  const int tx = threadIdx.x & 31, ty = threadIdx.x >> 5;
  const int n0 = blockIdx.x * 32, k0 = blockIdx.y * 32;
#pragma unroll
  for (int i = 0; i < 4; ++i)
    s[ty + i * 8][tx] = W[(size_t)(k0 + ty + i * 8) * 1024 + n0 + tx];
  __syncthreads();
#pragma unroll
  for (int i = 0; i < 4; ++i) {
    const int n = ty + i * 8;
    Tp[(size_t)(n0 + n) * 1024 + k0 + tx] = f2h(s[tx][n]);
  }
}

// ---------- fp16 MFMA GEMM, 256x256 tile, BK=64, burst-staged counted pipe --
// 8 waves as 2M x 4N; per-wave 128x64 output; 64 MFMA/wave/K-tile.
// LDS per K-tile: A/B each 2 halves of [8 oct][128 rows][8] (16KB) -> 64KB;
// double-buffered = 128KB. Schedule per K-tile: compute(buf c) -> barrier ->
// burst-stage tile kt+2 into buf c (8 loads/thread) -> vmcnt(8) [tile kt+1
// done, new 8 in flight] -> barrier -> flip. Latency hides under a full
// K-tile of compute instead of being drained every step.
// EPI: 1 bias+GELU->plane O | 5 QKV fused (col<2048 -> Q/K planes; else V^T)
template <int EPI>
__global__ __launch_bounds__(512, 2) void gemm256(
    const ushort* __restrict__ A, const ushort* __restrict__ B,
    const float* __restrict__ bias, float* __restrict__ C,
    ushort* __restrict__ O, int M, int N, int K) {
  __shared__ __align__(16) ushort sA[2][16384], sB[2][16384];
  const int t = threadIdx.x, w = t >> 6, lane = t & 63;
  const int llo = lane & 15, lhi = lane >> 4;
  const int wm = w >> 2, wn = w & 3;

  // XCD-aware bijective swizzle (grids 256 / 192 -> nwg % 8 == 0)
  const int gx = gridDim.x;
  int wg = blockIdx.y * gx + blockIdx.x;
  const int nwg = gx * gridDim.y;
  wg = (wg & 7) * (nwg >> 3) + (wg >> 3);
  const int bm = (wg / gx) * 256, bn = (wg % gx) * 256;

  // staging: load i (0,1) -> idx = i*8+w; ko = idx>>1 (oct), rb = (idx&1)*64
  const ushort* Ab = A + (size_t)(bm + lane) * K;
  const ushort* Bb = B + (size_t)(bn + lane) * K;
  const size_t K64 = (size_t)64 * K, K128 = (size_t)128 * K;

  auto STAGE_TILE = [&](int buf, int kb) {
#pragma unroll
    for (int i = 0; i < 2; ++i) {
      const int idx = i * 8 + w;
      const int ko = idx >> 1;
      const int rb = (idx & 1) << 6;
      const size_t go = (idx & 1) ? K64 : 0;
      const int lo = ko * 1024 + rb * 8;
      gl_lds16(Ab + go + kb + ko * 8, &sA[buf][lo]);
      gl_lds16(Ab + K128 + go + kb + ko * 8, &sA[buf][8192 + lo]);
      gl_lds16(Bb + go + kb + ko * 8, &sB[buf][lo]);
      gl_lds16(Bb + K128 + go + kb + ko * 8, &sB[buf][8192 + lo]);
    }
  };

  f32x4 acc[8][4] = {};
  const int NT = K >> 6;  // K-tiles of 64
  STAGE_TILE(0, 0);
  STAGE_TILE(1, 64);
  asm volatile("s_waitcnt vmcnt(8)" ::: "memory");  // tile 0 done
  asm volatile("s_barrier" ::: "memory");

  const int aoff = wm * 8192 + lhi * 1024;
  const int boff = (wn >> 1) * 8192 + lhi * 1024 + ((wn & 1) * 64 + llo) * 8;
  int cur = 0;
  for (int kt = 0; kt < NT; ++kt) {
    f16x8 af[8], bf4[4];
#pragma unroll
    for (int kk = 0; kk < 2; ++kk) {
      const int kof = kk * 4096;
#pragma unroll
      for (int f = 0; f < 8; ++f)
        af[f] = *(const f16x8*)&sA[cur][aoff + kof + (f * 16 + llo) * 8];
#pragma unroll
      for (int f = 0; f < 4; ++f)
        bf4[f] = *(const f16x8*)&sB[cur][boff + kof + f * 128];
#pragma unroll
      for (int fm = 0; fm < 8; ++fm)
#pragma unroll
        for (int fn = 0; fn < 4; ++fn)
          acc[fm][fn] = mfma16(af[fm], bf4[fn], acc[fm][fn]);
    }
    asm volatile("s_barrier" ::: "memory");  // all reads of buf[cur] done
    if (kt + 2 < NT) STAGE_TILE(cur, (kt + 2) << 6);  // burst into freed buf
    if (kt + 1 < NT) {
      if (kt + 2 < NT)
        asm volatile("s_waitcnt vmcnt(8)" ::: "memory");  // kt+1 complete
      else
        asm volatile("s_waitcnt vmcnt(0)" ::: "memory");
      asm volatile("s_barrier" ::: "memory");  // kt+1 visible to all waves
    }
    cur ^= 1;
  }

  // epilogue: C/D map col = lane&15, row = (lane>>4)*4 + r
#pragma unroll
  for (int fm = 0; fm < 8; ++fm) {
    const int row0 = bm + wm * 128 + fm * 16 + lhi * 4;
#pragma unroll
    for (int fn = 0; fn < 4; ++fn) {
      const int col = bn + wn * 64 + fn * 16 + llo;
      const float bc = bias[col];
      if (EPI == 5) {
        if (col < 2048) {
          const size_t base = (size_t)(col >> 10) * (4096 * 1024) + (col & 1023);
#pragma unroll
          for (int r = 0; r < 4; ++r)
            O[base + (size_t)(row0 + r) * 1024] = f2h(acc[fm][fn][r] + bc);
        } else {
          const int c = col - 2048;
          ushort4 vh;
#pragma unroll
          for (int r = 0; r < 4; ++r) ((ushort*)&vh)[r] = f2h(acc[fm][fn][r] + bc);
          const size_t o = (size_t)8 * 1024 * 1024 +
              ((size_t)(((row0 >> 9) * 32 + (c >> 5)) * 32 + (c & 31))) * 512 +
              (row0 & 511);
          *(ushort4*)(O + o) = vh;
        }
      } else {  // EPI == 1: GELU -> fp16 plane
#pragma unroll
        for (int r = 0; r < 4; ++r) {
          const size_t o = (size_t)(row0 + r) * N + col;
          float v = acc[fm][fn][r] + bc;
          v = 0.5f * v * (1.f + erff(v * 0.70710678118654752f));
          O[o] = f2h(v);
        }
      }
    }
  }
}

// ---------- fp16 MFMA GEMM, 128x128 tile, BK=32, dbuf 2-phase (r7 form) -----
// Used for Wo / FFN2 (N=1024 shapes) with split-K over blockIdx.z.
// EPI: 2 bias+res->C (KSPLIT: z0->C w/ bias+res, z1 raw->C2)
template <int EPI, int KSPLIT>
__global__ __launch_bounds__(256, 2) void gemm_mfma(
    const ushort* __restrict__ A, const ushort* __restrict__ B,
    const float* __restrict__ bias, const float* __restrict__ res,
    float* __restrict__ C, float* __restrict__ C2, ushort* __restrict__ O,
    int M, int N, int K) {
  __shared__ __align__(16) ushort sA[2][4096], sB[2][4096];
  const int t = threadIdx.x, w = t >> 6, lane = t & 63;
  const int llo = lane & 15, lhi = lane >> 4;
  const int wm = w >> 1, wn = w & 1;
  const int z = (KSPLIT > 1) ? blockIdx.z : 0;
  const int Ks = K / KSPLIT;

  const int gx = gridDim.x;
  int wg = blockIdx.y * gx + blockIdx.x;
  const int nwg = gx * gridDim.y;
  wg = (wg & 7) * (nwg >> 3) + (wg >> 3);
  const int bm = (wg / gx) * 128, bn = (wg % gx) * 128;

  const ushort* pA0 = A + (size_t)(bm + lane) * K + w * 8 + z * Ks;
  const ushort* pA1 = pA0 + (size_t)64 * K;
  const ushort* pB0 = B + (size_t)(bn + lane) * K + w * 8 + z * Ks;
  const ushort* pB1 = pB0 + (size_t)64 * K;

  auto STAGE = [&](int buf, int k0) {
    gl_lds16(pA0 + k0, &sA[buf][w * 1024]);
    gl_lds16(pA1 + k0, &sA[buf][w * 1024 + 512]);
    gl_lds16(pB0 + k0, &sB[buf][w * 1024]);
    gl_lds16(pB1 + k0, &sB[buf][w * 1024 + 512]);
  };

  f32x4 acc[4][4] = {};
  const int NT = Ks >> 5;
  STAGE(0, 0);
  __syncthreads();
  int cur = 0;
  for (int kt = 0; kt < NT; ++kt) {
    if (kt + 1 < NT) STAGE(cur ^ 1, (kt + 1) << 5);
    f16x8 a[4], bfr[4];
#pragma unroll
    for (int f = 0; f < 4; ++f) {
      a[f] = *(const f16x8*)&sA[cur][lhi * 1024 + (wm * 64 + f * 16 + llo) * 8];
      bfr[f] = *(const f16x8*)&sB[cur][lhi * 1024 + (wn * 64 + f * 16 + llo) * 8];
    }
#pragma unroll
    for (int fm = 0; fm < 4; ++fm)
#pragma unroll
      for (int fn = 0; fn < 4; ++fn)
        acc[fm][fn] = mfma16(a[fm], bfr[fn], acc[fm][fn]);
    __syncthreads();
    cur ^= 1;
  }

#pragma unroll
  for (int fm = 0; fm < 4; ++fm) {
    const int row0 = bm + wm * 64 + fm * 16 + lhi * 4;
#pragma unroll
    for (int fn = 0; fn < 4; ++fn) {
      const int col = bn + wn * 64 + fn * 16 + llo;
      const float bc = bias[col];
#pragma unroll
      for (int r = 0; r < 4; ++r) {
        const size_t o = (size_t)(row0 + r) * N + col;
        if (KSPLIT == 1 || z == 0)
          C[o] = acc[fm][fn][r] + bc + res[o];
        else
          C2[o] = acc[fm][fn][r];
      }
    }
  }
}

// ---------- fp16 MFMA flash attention per (b,h,zhalf): 512 threads ----------
// Swapped QK^T (S^T = K.Q^T); K slab [oct4][512][8]; V^T slab [koct64][32][8].
__global__ __launch_bounds__(512, 2) void attn_mfma(
    const ushort* __restrict__ Qg, const ushort* __restrict__ Kg,
    const ushort* __restrict__ Vg, const float* __restrict__ mask,
    const float* __restrict__ rel_l, ushort* __restrict__ Cg) {
  __shared__ __align__(16) ushort sK[16384], sV[16384];
  __shared__ __align__(16) ushort sP[5120];
  __shared__ float rel_s[1024];
  __shared__ float madd[512];

  const int h = blockIdx.x, b = blockIdx.y, z = blockIdx.z;
  const int t = threadIdx.x, w = t >> 6, lane = t & 63;
  const int llo = lane & 15, lhi = lane >> 4;
  const float SCALE = 0.17677669529663687f;  // 1/sqrt(32)

#pragma unroll
  for (int it = 0; it < 4; ++it) {
    const int task = t + it * 512;  // 0..2047
    const int s = task >> 2, oct = task & 3;
    const size_t g = (size_t)(b * 512 + s) * 1024 + h * 32 + oct * 8;
    *(uint4*)&sK[oct * 4096 + s * 8] = *(const uint4*)(Kg + g);
  }
#pragma unroll
  for (int it = 0; it < 4; ++it) {
    const int task = t + it * 512;  // 0..2047
    const int d = task >> 6, ko = task & 63;
    const size_t g = (size_t)((b * 32 + h) * 32 + d) * 512 + ko * 8;
    *(uint4*)&sV[ko * 256 + d * 8] = *(const uint4*)(Vg + g);
  }
  for (int i = t; i < 1023; i += 512) rel_s[i] = rel_l[(size_t)i * 32 + h];
  for (int i = t; i < 512; i += 512) madd[i] = (1.f - mask[b * 512 + i]) * -1e9f;
  __syncthreads();

  uint* wP = (uint*)(sP + w * 640 + llo * 40);
  const ushort* rP = sP + w * 640 + llo * 40;

  for (int qt = 0; qt < 2; ++qt) {
    const int q = z * 256 + w * 32 + qt * 16 + llo;
    const size_t qg = (size_t)(b * 512 + q) * 1024 + h * 32 + lhi * 8;
    const f16x8 fQ = *(const f16x8*)(Qg + qg);
    float m = -INFINITY, l = 0.f;
    f32x4 acc0 = {0.f, 0.f, 0.f, 0.f};
    f32x4 acc1 = {0.f, 0.f, 0.f, 0.f};

    for (int kt2 = 0; kt2 < 16; ++kt2) {
      float p[8];
      float tm = -INFINITY;
#pragma unroll
      for (int sub = 0; sub < 2; ++sub) {
        const int kt = kt2 * 2 + sub;
        const f16x8 fK = *(const f16x8*)&sK[lhi * 4096 + (kt * 16 + llo) * 8];
        f32x4 s4 = {0.f, 0.f, 0.f, 0.f};
        s4 = mfma16(fK, fQ, s4);
#pragma unroll
        for (int r = 0; r < 4; ++r) {
          const int k = kt * 16 + lhi * 4 + r;
          const float sv = (s4[r] + rel_s[q - k + 511]) * SCALE + madd[k];
          p[sub * 4 + r] = sv;
          tm = fmaxf(tm, sv);
        }
      }
      tm = fmaxf(tm, __shfl_xor(tm, 16));
      tm = fmaxf(tm, __shfl_xor(tm, 32));
      const float nm = fmaxf(m, tm);
      const float sc = __expf(m - nm);
      float ts = 0.f;
#pragma unroll
      for (int i = 0; i < 8; ++i) {
        p[i] = __expf(p[i] - nm);
        ts += p[i];
      }
      ts += __shfl_xor(ts, 16);
      ts += __shfl_xor(ts, 32);
      l = l * sc + ts;
      m = nm;
      acc0 *= sc;
      acc1 *= sc;
      // pack P into wave-private LDS in B-frag layout (fp16)
#pragma unroll
      for (int sub = 0; sub < 2; ++sub) {
        wP[sub * 8 + lhi * 2 + 0] =
            (uint)f2h(p[sub * 4 + 0]) | ((uint)f2h(p[sub * 4 + 1]) << 16);
        wP[sub * 8 + lhi * 2 + 1] =
            (uint)f2h(p[sub * 4 + 2]) | ((uint)f2h(p[sub * 4 + 3]) << 16);
      }
      const f16x8 fP = *(const f16x8*)(rP + lhi * 8);
      const int vb = (kt2 * 4 + lhi) * 256;
      const f16x8 fV0 = *(const f16x8*)&sV[vb + llo * 8];
      const f16x8 fV1 = *(const f16x8*)&sV[vb + (16 + llo) * 8];
      acc0 = mfma16(fV0, fP, acc0);
      acc1 = mfma16(fV1, fP, acc1);
    }

    const float invl = 1.f / l;
    const size_t ob = (size_t)(b * 512 + q) * 1024 + h * 32;
    ushort4 oh;
#pragma unroll
    for (int r = 0; r < 4; ++r) ((ushort*)&oh)[r] = f2h(acc0[r] * invl);
    *(ushort4*)(Cg + ob + lhi * 4) = oh;
#pragma unroll
    for (int r = 0; r < 4; ++r) ((ushort*)&oh)[r] = f2h(acc1[r] * invl);
    *(ushort4*)(Cg + ob + 16 + lhi * 4) = oh;
  }
}

// ---------- LayerNorm over rows of 1024 (optional 2nd addend, fp16 plane) ----
__global__ __launch_bounds__(256) void ln_kernel(
    const float* __restrict__ X, const float* __restrict__ X2,
    const float* __restrict__ g, const float* __restrict__ bt,
    float* __restrict__ out, ushort* __restrict__ O) {
  __shared__ float sb[4];
  const int row = blockIdx.x, t = threadIdx.x;
  float4 x = *(const float4*)&X[(size_t)row * 1024 + t * 4];
  if (X2) {
    const float4 y = *(const float4*)&X2[(size_t)row * 1024 + t * 4];
    x.x += y.x; x.y += y.y; x.z += y.z; x.w += y.w;
  }
  const float s = block_reduce_sum(x.x + x.y + x.z + x.w, sb);
  const float mu = s * (1.f / 1024.f);
  const float dx = x.x - mu, dy = x.y - mu, dz = x.z - mu, dw = x.w - mu;
  const float ss = block_reduce_sum(dx * dx + dy * dy + dz * dz + dw * dw, sb);
  const float rs = rsqrtf(ss * (1.f / 1024.f) + 1e-12f);
  const float4 gv = *(const float4*)&g[t * 4];
  const float4 bv = *(const float4*)&bt[t * 4];
  float4 o;
  o.x = dx * rs * gv.x + bv.x;
  o.y = dy * rs * gv.y + bv.y;
  o.z = dz * rs * gv.z + bv.z;
  o.w = dw * rs * gv.w + bv.w;
  *(float4*)&out[(size_t)row * 1024 + t * 4] = o;
  if (O) {
    ushort4 vh;
    vh.x = f2h(o.x); vh.y = f2h(o.y); vh.z = f2h(o.z); vh.w = f2h(o.w);
    *(ushort4*)&O[(size_t)row * 1024 + t * 4] = vh;
  }
}

// ---------- pooling stage 1: s-split partials ----------
__global__ __launch_bounds__(128) void pool_part(
    const float* __restrict__ X, const float* __restrict__ mask,
    float* __restrict__ psum, float* __restrict__ pmax,
    float* __restrict__ pcnt) {
  const int cb = blockIdx.x, b = blockIdx.y, sb = blockIdx.z;
  const int col = cb * 128 + threadIdx.x;
  float sum = 0.f, mx = -INFINITY, cnt = 0.f;
  for (int i = 0; i < 128; ++i) {
    const int s = sb * 128 + i;
    const float v = X[(size_t)(b * 512 + s) * 1024 + col];
    const float mk = mask[b * 512 + s];
    sum = fmaf(v, mk, sum);
    cnt += mk;
    mx = fmaxf(mx, v + (1.f - mk) * -1e9f);
  }
  psum[(size_t)(sb * 8 + b) * 1024 + col] = sum;
  pmax[(size_t)(sb * 8 + b) * 1024 + col] = mx;
  if (cb == 0 && threadIdx.x == 0) pcnt[sb * 8 + b] = cnt;
}

// ---------- pooling finalize: mean + max + first token ----------
__global__ __launch_bounds__(256) void pool_fin(
    const float* __restrict__ X, const float* __restrict__ psum,
    const float* __restrict__ pmax, const float* __restrict__ pcnt,
    float* __restrict__ pooled) {
  const int idx = blockIdx.x * 256 + threadIdx.x;  // 0..8191
  const int b = idx >> 10, col = idx & 1023;
  float s = 0.f, m = -INFINITY, c = 0.f;
#pragma unroll
  for (int sb = 0; sb < 4; ++sb) {
    s += psum[(size_t)(sb * 8 + b) * 1024 + col];
    m = fmaxf(m, pmax[(size_t)(sb * 8 + b) * 1024 + col]);
    c += pcnt[sb * 8 + b];
  }
  pooled[(size_t)b * 3072 + col] = s / c;
  pooled[(size_t)b * 3072 + 1024 + col] = m;
  pooled[(size_t)b * 3072 + 2048 + col] = X[(size_t)(b * 512) * 1024 + col];
}

// ---------- pooled GEMM stage 1: split-K partials ----------
__global__ __launch_bounds__(256) void pgemm_part(
    const float* __restrict__ P, const float* __restrict__ W,
    float* __restrict__ part) {
  __shared__ float sP[8][192];
  __shared__ float sacc[256][9];
  const int nb = blockIdx.x, kb = blockIdx.y;
  const int t = threadIdx.x;
  const int k0 = kb * 192, n0 = nb * 64;
  for (int i = t; i < 1536; i += 256)
    sP[i / 192][i % 192] = P[(size_t)(i / 192) * 3072 + k0 + i % 192];
  __syncthreads();
  const int n = t & 63, kq = t >> 6;
  float acc[8] = {};
  for (int kk = 0; kk < 48; ++kk) {
    const int k = kq * 48 + kk;
    const float wv = W[(size_t)(k0 + k) * 1024 + n0 + n];
#pragma unroll
    for (int b = 0; b < 8; ++b) acc[b] = fmaf(sP[b][k], wv, acc[b]);
  }
#pragma unroll
  for (int b = 0; b < 8; ++b) sacc[t][b] = acc[b];
  __syncthreads();
  for (int p = t; p < 512; p += 256) {
    const int b = p >> 6, nn = p & 63;
    const float v = sacc[nn][b] + sacc[64 + nn][b] + sacc[128 + nn][b] +
                    sacc[192 + nn][b];
    part[((size_t)kb * 8 + b) * 1024 + n0 + nn] = v;
  }
}

// ---------- pooled GEMM finalize ----------
__global__ __launch_bounds__(256) void pgemm_fin(
    const float* __restrict__ part, const float* __restrict__ bias,
    float* __restrict__ out) {
  const int idx = blockIdx.x * 256 + threadIdx.x;  // 0..8191
  const int b = idx >> 10, n = idx & 1023;
  float v = bias[n];
#pragma unroll
  for (int kb = 0; kb < 16; ++kb) v += part[((size_t)kb * 8 + b) * 1024 + n];
  out[(size_t)b * 1024 + n] = v;
}

// ---------- classifier: one block per (n,b), wave-reduce over K ----------
__global__ __launch_bounds__(64) void cls_kernel(
    const float* __restrict__ X, const float* __restrict__ W,
    const float* __restrict__ bias, float* __restrict__ out) {
  const int n = blockIdx.x, b = blockIdx.y, lane = threadIdx.x;
  float a = 0.f;
#pragma unroll
  for (int i = 0; i < 16; ++i) {
    const int k = lane + i * 64;
    a = fmaf(X[(size_t)b * 1024 + k], W[(size_t)k * 20 + n], a);
  }
#pragma unroll
  for (int o = 32; o > 0; o >>= 1) a += __shfl_down(a, o, 64);
  if (lane == 0) out[b * 20 + n] = a + bias[n];
}

extern "C" void kernel_launch(void* const* d_in, const int* in_sizes, int n_in,
                              void* d_out, int out_size, void* d_ws, size_t ws_size,
                              hipStream_t stream) {
  const float* hs    = (const float*)d_in[0];
  const float* amask = (const float*)d_in[1];
  const float* Wq    = (const float*)d_in[2];
  const float* bq    = (const float*)d_in[3];
  const float* Wk    = (const float*)d_in[4];
  const float* bk    = (const float*)d_in[5];
  const float* Wv    = (const float*)d_in[6];
  const float* bv    = (const float*)d_in[7];
  const float* Wo    = (const float*)d_in[8];
  const float* bo    = (const float*)d_in[9];
  const float* ln1g  = (const float*)d_in[10];
  const float* ln1b  = (const float*)d_in[11];
  const float* W1    = (const float*)d_in[12];
  const float* b1    = (const float*)d_in[13];
  const float* W2    = (const float*)d_in[14];
  const float* b2    = (const float*)d_in[15];
  const float* ln2g  = (const float*)d_in[16];
  const float* ln2b  = (const float*)d_in[17];
  const float* rel   = (const float*)d_in[18];
  const float* poolW = (const float*)d_in[19];
  const float* poolb = (const float*)d_in[20];
  const float* plng  = (const float*)d_in[21];
  const float* plnb  = (const float*)d_in[22];
  const float* clsW  = (const float*)d_in[23];
  const float* clsb  = (const float*)d_in[24];

  char* W = (char*)d_ws;
  const size_t MB = (size_t)1 << 20;
  const size_t QK = (size_t)4096 * 1024;  // Q/K plane stride (elements)
  float* buf_t  = (float*)(W + 0 * MB);    // 16MB fp32
  float* buf_t2 = (float*)(W + 16 * MB);   // 16MB fp32 (split-K partials)
  float* buf_h1 = (float*)(W + 32 * MB);   // 16MB fp32
  float* buf_x  = (float*)(W + 48 * MB);   // 16MB fp32
  ushort* PL  = (ushort*)(W + 64 * MB);    // Q(0..4M) K(4..8M) V^T(8..12M), 24MB
  ushort* CTX = (ushort*)(W + 88 * MB);    // 8MB; also next-layer X plane
  ushort* Xp  = CTX;
  ushort* H1  = (ushort*)(W + 96 * MB);    // 8MB
  ushort* F1  = (ushort*)(W + 104 * MB);   // 32MB
  ushort* Wt  = (ushort*)(W + 136 * MB);   // 6MB ([3072][1024] fp16)
  float* bcat = (float*)(W + 142 * MB);    // 12KB
  float* sm   = (float*)(W + 143 * MB);    // small-buffer region (<1.5MB)
  float* pooled  = sm;                     // 8*3072
  float* pool_h  = pooled + 8 * 3072;      // 8*1024
  float* pool_h2 = pool_h + 8 * 1024;      // 8*1024
  float* pcnt    = pool_h2 + 8 * 1024;     // 32
  float* psum    = pcnt + 64;              // 4*8*1024
  float* pmax    = psum + 4 * 8 * 1024;    // 4*8*1024
  float* pgpart  = pmax + 4 * 8 * 1024;    // 16*8*1024

  const int n4act = (4096 * 1024) / 4;
  const dim3 gQKV(3072 / 256, 4096 / 256);  // 12 x 16 = 192 blocks, 512 thr
  const dim3 gF1(4096 / 256, 4096 / 256);   // 16 x 16 = 256 blocks, 512 thr
  const dim3 gKS(1024 / 128, 32, 2);        // 512 blocks (Wo, FFN2 split-K)
  const dim3 wsQ3(32, 32, 3);

  acast<<<n4act / 256, 256, 0, stream>>>(hs, Xp, n4act);

  const float* x_in = hs;
  for (int l = 0; l < 4; ++l) {
    const float* Wq_l = Wq + (size_t)l * 1024 * 1024;
    const float* Wk_l = Wk + (size_t)l * 1024 * 1024;
    const float* Wv_l = Wv + (size_t)l * 1024 * 1024;
    const float* Wo_l = Wo + (size_t)l * 1024 * 1024;
    const float* W1_l = W1 + (size_t)l * 1024 * 4096;
    const float* W2_l = W2 + (size_t)l * 4096 * 1024;

    // fused QKV (256^2 burst-counted tile)
    concat3<<<12, 256, 0, stream>>>(bq + l * 1024, bk + l * 1024, bv + l * 1024, bcat);
    wcast_t3<<<wsQ3, 256, 0, stream>>>(Wq_l, Wk_l, Wv_l, Wt);
    gemm256<5><<<gQKV, 512, 0, stream>>>(Xp, Wt, bcat, nullptr, PL,
                                         4096, 3072, 1024);

    attn_mfma<<<dim3(32, 8, 2), 512, 0, stream>>>(
        PL, PL + QK, PL + 2 * QK, amask, rel + (size_t)l * 1023 * 32, CTX);

    wcast_t<<<dim3(32, 32), 256, 0, stream>>>(Wo_l, Wt, 1024, 1024);
    gemm_mfma<2, 2><<<gKS, 256, 0, stream>>>(CTX, Wt, bo + l * 1024, x_in,
                                             buf_t, buf_t2, nullptr, 4096, 1024, 1024);
    ln_kernel<<<4096, 256, 0, stream>>>(buf_t, buf_t2, ln1g + l * 1024,
                                        ln1b + l * 1024, buf_h1, H1);

    // FFN1 (256^2 burst-counted tile)
    wcast_t<<<dim3(4096 / 32, 1024 / 32), 256, 0, stream>>>(W1_l, Wt, 1024, 4096);
    gemm256<1><<<gF1, 512, 0, stream>>>(H1, Wt, b1 + l * 4096, nullptr, F1,
                                        4096, 4096, 1024);
    wcast_t<<<dim3(1024 / 32, 4096 / 32), 256, 0, stream>>>(W2_l, Wt, 4096, 1024);
    gemm_mfma<2, 2><<<gKS, 256, 0, stream>>>(F1, Wt, b2 + l * 1024, buf_h1,
                                             buf_t, buf_t2, nullptr, 4096, 1024, 4096);
    ln_kernel<<<4096, 256, 0, stream>>>(buf_t, buf_t2, ln2g + l * 1024,
                                        ln2b + l * 1024, buf_x, Xp);
    x_in = buf_x;
  }

  pool_part<<<dim3(8, 8, 4), 128, 0, stream>>>(buf_x, amask, psum, pmax, pcnt);
  pool_fin<<<32, 256, 0, stream>>>(buf_x, psum, pmax, pcnt, pooled);
  pgemm_part<<<dim3(16, 16), 256, 0, stream>>>(pooled, poolW, pgpart);
  pgemm_fin<<<32, 256, 0, stream>>>(pgpart, poolb, pool_h);
  ln_kernel<<<8, 256, 0, stream>>>(pool_h, nullptr, plng, plnb, pool_h2, nullptr);
  cls_kernel<<<dim3(20, 8), 64, 0, stream>>>(pool_h2, clsW, clsb, (float*)d_out);
}

// Round 12
// 1318.743 us; speedup vs baseline: 1.0665x; 1.0162x over previous
//
#include <hip/hip_runtime.h>
#include <math.h>

typedef __attribute__((ext_vector_type(8))) _Float16 f16x8;
typedef __attribute__((ext_vector_type(4))) float f32x4;

// ---------- fp16 helpers ----------
__device__ __forceinline__ ushort f2h(float x) {
  union { _Float16 h; ushort u; } c;
  c.h = (_Float16)x;
  return c.u;
}
__device__ __forceinline__ void gl_lds16(const ushort* g, ushort* l) {
  __builtin_amdgcn_global_load_lds(
      (const __attribute__((address_space(1))) unsigned int*)g,
      (__attribute__((address_space(3))) unsigned int*)l, 16, 0, 0);
}
__device__ __forceinline__ f32x4 mfma16(f16x8 a, f16x8 b, f32x4 c) {
  return __builtin_amdgcn_mfma_f32_16x16x32_f16(a, b, c, 0, 0, 0);
}
// tanh-form GELU (|err| vs erf-GELU <= ~2e-3, far under tolerance)
__device__ __forceinline__ float gelu_t(float v) {
  const float u = v * (0.7978845608f + 0.0356774081f * v * v);
  const float e = __expf(2.f * u);
  return v * (e / (e + 1.f));  // 0.5*v*(1+tanh(u)) == v*sigmoid(2u)
}

// ---------- block-wide sum reduce (256 threads = 4 waves) ----------
__device__ __forceinline__ float block_reduce_sum(float v, float* sb) {
#pragma unroll
  for (int o = 32; o > 0; o >>= 1) v += __shfl_down(v, o, 64);
  const int t = threadIdx.x;
  if ((t & 63) == 0) sb[t >> 6] = v;
  __syncthreads();
  v = sb[0] + sb[1] + sb[2] + sb[3];
  __syncthreads();
  return v;
}

// ---------- activation cast: fp32 -> fp16 plane ----------
__global__ __launch_bounds__(256) void acast(const float* __restrict__ X,
                                             ushort* __restrict__ H, int n4) {
  const int i = blockIdx.x * 256 + threadIdx.x;
  if (i >= n4) return;
  const float4 x = ((const float4*)X)[i];
  ushort4 h;
  h.x = f2h(x.x); h.y = f2h(x.y); h.z = f2h(x.z); h.w = f2h(x.w);
  ((ushort4*)H)[i] = h;
}

// ---------- weight transpose+cast: W[K,N] fp32 -> T [N,K] fp16 ----------
__global__ __launch_bounds__(256) void wcast_t(const float* __restrict__ W,
                                               ushort* __restrict__ T,
                                               int K, int N) {
  __shared__ float s[32][33];
  const int tx = threadIdx.x & 31, ty = threadIdx.x >> 5;
  const int n0 = blockIdx.x * 32, k0 = blockIdx.y * 32;
#pragma unroll
  for (int i = 0; i < 4; ++i)
    s[ty + i * 8][tx] = W[(size_t)(k0 + ty + i * 8) * N + n0 + tx];
  __syncthreads();
#pragma unroll
  for (int i = 0; i < 4; ++i) {
    const int n = ty + i * 8;
    T[(size_t)(n0 + n) * K + k0 + tx] = f2h(s[tx][n]);
  }
}

// ---------- fused QKV weight transpose (3x 1024x1024) ----------
__global__ __launch_bounds__(256) void wcast_t3(const float* __restrict__ W0,
                                                const float* __restrict__ W1,
                                                const float* __restrict__ W2,
                                                ushort* __restrict__ T) {
  __shared__ float s[32][33];
  const float* W = blockIdx.z == 0 ? W0 : (blockIdx.z == 1 ? W1 : W2);
  ushort* Tp = T + (size_t)blockIdx.z * 1024 * 1024;
  const int tx = threadIdx.x & 31, ty = threadIdx.x >> 5;
  const int n0 = blockIdx.x * 32, k0 = blockIdx.y * 32;
#pragma unroll
  for (int i = 0; i < 4; ++i)
    s[ty + i * 8][tx] = W[(size_t)(k0 + ty + i * 8) * 1024 + n0 + tx];
  __syncthreads();
#pragma unroll
  for (int i = 0; i < 4; ++i) {
    const int n = ty + i * 8;
    Tp[(size_t)(n0 + n) * 1024 + k0 + tx] = f2h(s[tx][n]);
  }
}

// ---------- fp16 MFMA GEMM, 256x256 tile, BK=64, burst-staged counted pipe --
// EPI: 1 bias+GELU->plane O | 5 QKV fused (bias from b1/b2/b3 by col range;
//      col<2048 -> Q/K planes; else V^T)
template <int EPI>
__global__ __launch_bounds__(512, 2) void gemm256(
    const ushort* __restrict__ A, const ushort* __restrict__ B,
    const float* __restrict__ bias, const float* __restrict__ bias2,
    const float* __restrict__ bias3, ushort* __restrict__ O,
    int M, int N, int K) {
  __shared__ __align__(16) ushort sA[2][16384], sB[2][16384];
  const int t = threadIdx.x, w = t >> 6, lane = t & 63;
  const int llo = lane & 15, lhi = lane >> 4;
  const int wm = w >> 2, wn = w & 3;

  // XCD-aware bijective swizzle (grids 256 / 192 -> nwg % 8 == 0)
  const int gx = gridDim.x;
  int wg = blockIdx.y * gx + blockIdx.x;
  const int nwg = gx * gridDim.y;
  wg = (wg & 7) * (nwg >> 3) + (wg >> 3);
  const int bm = (wg / gx) * 256, bn = (wg % gx) * 256;

  const ushort* Ab = A + (size_t)(bm + lane) * K;
  const ushort* Bb = B + (size_t)(bn + lane) * K;
  const size_t K64 = (size_t)64 * K, K128 = (size_t)128 * K;

  auto STAGE_TILE = [&](int buf, int kb) {
#pragma unroll
    for (int i = 0; i < 2; ++i) {
      const int idx = i * 8 + w;
      const int ko = idx >> 1;
      const int rb = (idx & 1) << 6;
      const size_t go = (idx & 1) ? K64 : 0;
      const int lo = ko * 1024 + rb * 8;
      gl_lds16(Ab + go + kb + ko * 8, &sA[buf][lo]);
      gl_lds16(Ab + K128 + go + kb + ko * 8, &sA[buf][8192 + lo]);
      gl_lds16(Bb + go + kb + ko * 8, &sB[buf][lo]);
      gl_lds16(Bb + K128 + go + kb + ko * 8, &sB[buf][8192 + lo]);
    }
  };

  f32x4 acc[8][4] = {};
  const int NT = K >> 6;  // K-tiles of 64
  STAGE_TILE(0, 0);
  STAGE_TILE(1, 64);
  asm volatile("s_waitcnt vmcnt(8)" ::: "memory");  // tile 0 done
  asm volatile("s_barrier" ::: "memory");

  const int aoff = wm * 8192 + lhi * 1024;
  const int boff = (wn >> 1) * 8192 + lhi * 1024 + ((wn & 1) * 64 + llo) * 8;
  int cur = 0;
  for (int kt = 0; kt < NT; ++kt) {
    f16x8 af[8], bf4[4];
#pragma unroll
    for (int kk = 0; kk < 2; ++kk) {
      const int kof = kk * 4096;
#pragma unroll
      for (int f = 0; f < 8; ++f)
        af[f] = *(const f16x8*)&sA[cur][aoff + kof + (f * 16 + llo) * 8];
#pragma unroll
      for (int f = 0; f < 4; ++f)
        bf4[f] = *(const f16x8*)&sB[cur][boff + kof + f * 128];
      __builtin_amdgcn_s_setprio(1);
#pragma unroll
      for (int fm = 0; fm < 8; ++fm)
#pragma unroll
        for (int fn = 0; fn < 4; ++fn)
          acc[fm][fn] = mfma16(af[fm], bf4[fn], acc[fm][fn]);
      __builtin_amdgcn_s_setprio(0);
    }
    asm volatile("s_barrier" ::: "memory");  // all reads of buf[cur] done
    if (kt + 2 < NT) STAGE_TILE(cur, (kt + 2) << 6);  // burst into freed buf
    if (kt + 1 < NT) {
      if (kt + 2 < NT)
        asm volatile("s_waitcnt vmcnt(8)" ::: "memory");  // kt+1 complete
      else
        asm volatile("s_waitcnt vmcnt(0)" ::: "memory");
      asm volatile("s_barrier" ::: "memory");  // kt+1 visible to all waves
    }
    cur ^= 1;
  }

  // epilogue: C/D map col = lane&15, row = (lane>>4)*4 + r
#pragma unroll
  for (int fm = 0; fm < 8; ++fm) {
    const int row0 = bm + wm * 128 + fm * 16 + lhi * 4;
#pragma unroll
    for (int fn = 0; fn < 4; ++fn) {
      const int col = bn + wn * 64 + fn * 16 + llo;
      float bc;
      if (EPI == 5)
        bc = col < 1024 ? bias[col]
                        : (col < 2048 ? bias2[col - 1024] : bias3[col - 2048]);
      else
        bc = bias[col];
      if (EPI == 5) {
        if (col < 2048) {
          const size_t base = (size_t)(col >> 10) * (4096 * 1024) + (col & 1023);
#pragma unroll
          for (int r = 0; r < 4; ++r)
            O[base + (size_t)(row0 + r) * 1024] = f2h(acc[fm][fn][r] + bc);
        } else {
          const int c = col - 2048;
          ushort4 vh;
#pragma unroll
          for (int r = 0; r < 4; ++r) ((ushort*)&vh)[r] = f2h(acc[fm][fn][r] + bc);
          const size_t o = (size_t)8 * 1024 * 1024 +
              ((size_t)(((row0 >> 9) * 32 + (c >> 5)) * 32 + (c & 31))) * 512 +
              (row0 & 511);
          *(ushort4*)(O + o) = vh;
        }
      } else {  // EPI == 1: GELU -> fp16 plane
#pragma unroll
        for (int r = 0; r < 4; ++r) {
          const size_t o = (size_t)(row0 + r) * N + col;
          O[o] = f2h(gelu_t(acc[fm][fn][r] + bc));
        }
      }
    }
  }
}

// ---------- fp16 MFMA GEMM, 128x128 tile, BK=32, dbuf 2-phase (r7 form) -----
// Used for Wo / FFN2 (N=1024 shapes) with split-K over blockIdx.z.
// EPI: 2 bias+res->C (KSPLIT: z0->C w/ bias+res, z1 raw->C2)
template <int EPI, int KSPLIT>
__global__ __launch_bounds__(256, 2) void gemm_mfma(
    const ushort* __restrict__ A, const ushort* __restrict__ B,
    const float* __restrict__ bias, const float* __restrict__ res,
    float* __restrict__ C, float* __restrict__ C2, ushort* __restrict__ O,
    int M, int N, int K) {
  __shared__ __align__(16) ushort sA[2][4096], sB[2][4096];
  const int t = threadIdx.x, w = t >> 6, lane = t & 63;
  const int llo = lane & 15, lhi = lane >> 4;
  const int wm = w >> 1, wn = w & 1;
  const int z = (KSPLIT > 1) ? blockIdx.z : 0;
  const int Ks = K / KSPLIT;

  const int gx = gridDim.x;
  int wg = blockIdx.y * gx + blockIdx.x;
  const int nwg = gx * gridDim.y;
  wg = (wg & 7) * (nwg >> 3) + (wg >> 3);
  const int bm = (wg / gx) * 128, bn = (wg % gx) * 128;

  const ushort* pA0 = A + (size_t)(bm + lane) * K + w * 8 + z * Ks;
  const ushort* pA1 = pA0 + (size_t)64 * K;
  const ushort* pB0 = B + (size_t)(bn + lane) * K + w * 8 + z * Ks;
  const ushort* pB1 = pB0 + (size_t)64 * K;

  auto STAGE = [&](int buf, int k0) {
    gl_lds16(pA0 + k0, &sA[buf][w * 1024]);
    gl_lds16(pA1 + k0, &sA[buf][w * 1024 + 512]);
    gl_lds16(pB0 + k0, &sB[buf][w * 1024]);
    gl_lds16(pB1 + k0, &sB[buf][w * 1024 + 512]);
  };

  f32x4 acc[4][4] = {};
  const int NT = Ks >> 5;
  STAGE(0, 0);
  __syncthreads();
  int cur = 0;
  for (int kt = 0; kt < NT; ++kt) {
    if (kt + 1 < NT) STAGE(cur ^ 1, (kt + 1) << 5);
    f16x8 a[4], bfr[4];
#pragma unroll
    for (int f = 0; f < 4; ++f) {
      a[f] = *(const f16x8*)&sA[cur][lhi * 1024 + (wm * 64 + f * 16 + llo) * 8];
      bfr[f] = *(const f16x8*)&sB[cur][lhi * 1024 + (wn * 64 + f * 16 + llo) * 8];
    }
    __builtin_amdgcn_s_setprio(1);
#pragma unroll
    for (int fm = 0; fm < 4; ++fm)
#pragma unroll
      for (int fn = 0; fn < 4; ++fn)
        acc[fm][fn] = mfma16(a[fm], bfr[fn], acc[fm][fn]);
    __builtin_amdgcn_s_setprio(0);
    __syncthreads();
    cur ^= 1;
  }

#pragma unroll
  for (int fm = 0; fm < 4; ++fm) {
    const int row0 = bm + wm * 64 + fm * 16 + lhi * 4;
#pragma unroll
    for (int fn = 0; fn < 4; ++fn) {
      const int col = bn + wn * 64 + fn * 16 + llo;
      const float bc = bias[col];
#pragma unroll
      for (int r = 0; r < 4; ++r) {
        const size_t o = (size_t)(row0 + r) * N + col;
        if (KSPLIT == 1 || z == 0)
          C[o] = acc[fm][fn][r] + bc + res[o];
        else
          C2[o] = acc[fm][fn][r];
      }
    }
  }
}

// ---------- fp16 MFMA flash attention per (b,h,zhalf): 512 threads ----------
__global__ __launch_bounds__(512, 2) void attn_mfma(
    const ushort* __restrict__ Qg, const ushort* __restrict__ Kg,
    const ushort* __restrict__ Vg, const float* __restrict__ mask,
    const float* __restrict__ rel_l, ushort* __restrict__ Cg) {
  __shared__ __align__(16) ushort sK[16384], sV[16384];
  __shared__ __align__(16) ushort sP[5120];
  __shared__ float rel_s[1024];
  __shared__ float madd[512];

  const int h = blockIdx.x, b = blockIdx.y, z = blockIdx.z;
  const int t = threadIdx.x, w = t >> 6, lane = t & 63;
  const int llo = lane & 15, lhi = lane >> 4;
  const float SCALE = 0.17677669529663687f;  // 1/sqrt(32)

#pragma unroll
  for (int it = 0; it < 4; ++it) {
    const int task = t + it * 512;
    const int s = task >> 2, oct = task & 3;
    const size_t g = (size_t)(b * 512 + s) * 1024 + h * 32 + oct * 8;
    *(uint4*)&sK[oct * 4096 + s * 8] = *(const uint4*)(Kg + g);
  }
#pragma unroll
  for (int it = 0; it < 4; ++it) {
    const int task = t + it * 512;
    const int d = task >> 6, ko = task & 63;
    const size_t g = (size_t)((b * 32 + h) * 32 + d) * 512 + ko * 8;
    *(uint4*)&sV[ko * 256 + d * 8] = *(const uint4*)(Vg + g);
  }
  for (int i = t; i < 1023; i += 512) rel_s[i] = rel_l[(size_t)i * 32 + h];
  for (int i = t; i < 512; i += 512) madd[i] = (1.f - mask[b * 512 + i]) * -1e9f;
  __syncthreads();

  uint* wP = (uint*)(sP + w * 640 + llo * 40);
  const ushort* rP = sP + w * 640 + llo * 40;

  for (int qt = 0; qt < 2; ++qt) {
    const int q = z * 256 + w * 32 + qt * 16 + llo;
    const size_t qg = (size_t)(b * 512 + q) * 1024 + h * 32 + lhi * 8;
    const f16x8 fQ = *(const f16x8*)(Qg + qg);
    float m = -INFINITY, l = 0.f;
    f32x4 acc0 = {0.f, 0.f, 0.f, 0.f};
    f32x4 acc1 = {0.f, 0.f, 0.f, 0.f};

    for (int kt2 = 0; kt2 < 16; ++kt2) {
      float p[8];
      float tm = -INFINITY;
#pragma unroll
      for (int sub = 0; sub < 2; ++sub) {
        const int kt = kt2 * 2 + sub;
        const f16x8 fK = *(const f16x8*)&sK[lhi * 4096 + (kt * 16 + llo) * 8];
        f32x4 s4 = {0.f, 0.f, 0.f, 0.f};
        s4 = mfma16(fK, fQ, s4);
#pragma unroll
        for (int r = 0; r < 4; ++r) {
          const int k = kt * 16 + lhi * 4 + r;
          const float sv = (s4[r] + rel_s[q - k + 511]) * SCALE + madd[k];
          p[sub * 4 + r] = sv;
          tm = fmaxf(tm, sv);
        }
      }
      tm = fmaxf(tm, __shfl_xor(tm, 16));
      tm = fmaxf(tm, __shfl_xor(tm, 32));
      const float nm = fmaxf(m, tm);
      const float sc = __expf(m - nm);
      float ts = 0.f;
#pragma unroll
      for (int i = 0; i < 8; ++i) {
        p[i] = __expf(p[i] - nm);
        ts += p[i];
      }
      ts += __shfl_xor(ts, 16);
      ts += __shfl_xor(ts, 32);
      l = l * sc + ts;
      m = nm;
      acc0 *= sc;
      acc1 *= sc;
#pragma unroll
      for (int sub = 0; sub < 2; ++sub) {
        wP[sub * 8 + lhi * 2 + 0] =
            (uint)f2h(p[sub * 4 + 0]) | ((uint)f2h(p[sub * 4 + 1]) << 16);
        wP[sub * 8 + lhi * 2 + 1] =
            (uint)f2h(p[sub * 4 + 2]) | ((uint)f2h(p[sub * 4 + 3]) << 16);
      }
      const f16x8 fP = *(const f16x8*)(rP + lhi * 8);
      const int vb = (kt2 * 4 + lhi) * 256;
      const f16x8 fV0 = *(const f16x8*)&sV[vb + llo * 8];
      const f16x8 fV1 = *(const f16x8*)&sV[vb + (16 + llo) * 8];
      acc0 = mfma16(fV0, fP, acc0);
      acc1 = mfma16(fV1, fP, acc1);
    }

    const float invl = 1.f / l;
    const size_t ob = (size_t)(b * 512 + q) * 1024 + h * 32;
    ushort4 oh;
#pragma unroll
    for (int r = 0; r < 4; ++r) ((ushort*)&oh)[r] = f2h(acc0[r] * invl);
    *(ushort4*)(Cg + ob + lhi * 4) = oh;
#pragma unroll
    for (int r = 0; r < 4; ++r) ((ushort*)&oh)[r] = f2h(acc1[r] * invl);
    *(ushort4*)(Cg + ob + 16 + lhi * 4) = oh;
  }
}

// ---------- LayerNorm over rows of 1024 (optional 2nd addend, fp16 plane) ----
__global__ __launch_bounds__(256) void ln_kernel(
    const float* __restrict__ X, const float* __restrict__ X2,
    const float* __restrict__ g, const float* __restrict__ bt,
    float* __restrict__ out, ushort* __restrict__ O) {
  __shared__ float sb[4];
  const int row = blockIdx.x, t = threadIdx.x;
  float4 x = *(const float4*)&X[(size_t)row * 1024 + t * 4];
  if (X2) {
    const float4 y = *(const float4*)&X2[(size_t)row * 1024 + t * 4];
    x.x += y.x; x.y += y.y; x.z += y.z; x.w += y.w;
  }
  const float s = block_reduce_sum(x.x + x.y + x.z + x.w, sb);
  const float mu = s * (1.f / 1024.f);
  const float dx = x.x - mu, dy = x.y - mu, dz = x.z - mu, dw = x.w - mu;
  const float ss = block_reduce_sum(dx * dx + dy * dy + dz * dz + dw * dw, sb);
  const float rs = rsqrtf(ss * (1.f / 1024.f) + 1e-12f);
  const float4 gv = *(const float4*)&g[t * 4];
  const float4 bv = *(const float4*)&bt[t * 4];
  float4 o;
  o.x = dx * rs * gv.x + bv.x;
  o.y = dy * rs * gv.y + bv.y;
  o.z = dz * rs * gv.z + bv.z;
  o.w = dw * rs * gv.w + bv.w;
  *(float4*)&out[(size_t)row * 1024 + t * 4] = o;
  if (O) {
    ushort4 vh;
    vh.x = f2h(o.x); vh.y = f2h(o.y); vh.z = f2h(o.z); vh.w = f2h(o.w);
    *(ushort4*)&O[(size_t)row * 1024 + t * 4] = vh;
  }
}

// ---------- pooling stage 1: s-split partials ----------
__global__ __launch_bounds__(128) void pool_part(
    const float* __restrict__ X, const float* __restrict__ mask,
    float* __restrict__ psum, float* __restrict__ pmax,
    float* __restrict__ pcnt) {
  const int cb = blockIdx.x, b = blockIdx.y, sb = blockIdx.z;
  const int col = cb * 128 + threadIdx.x;
  float sum = 0.f, mx = -INFINITY, cnt = 0.f;
  for (int i = 0; i < 128; ++i) {
    const int s = sb * 128 + i;
    const float v = X[(size_t)(b * 512 + s) * 1024 + col];
    const float mk = mask[b * 512 + s];
    sum = fmaf(v, mk, sum);
    cnt += mk;
    mx = fmaxf(mx, v + (1.f - mk) * -1e9f);
  }
  psum[(size_t)(sb * 8 + b) * 1024 + col] = sum;
  pmax[(size_t)(sb * 8 + b) * 1024 + col] = mx;
  if (cb == 0 && threadIdx.x == 0) pcnt[sb * 8 + b] = cnt;
}

// ---------- pooling finalize: mean + max + first token ----------
__global__ __launch_bounds__(256) void pool_fin(
    const float* __restrict__ X, const float* __restrict__ psum,
    const float* __restrict__ pmax, const float* __restrict__ pcnt,
    float* __restrict__ pooled) {
  const int idx = blockIdx.x * 256 + threadIdx.x;
  const int b = idx >> 10, col = idx & 1023;
  float s = 0.f, m = -INFINITY, c = 0.f;
#pragma unroll
  for (int sb = 0; sb < 4; ++sb) {
    s += psum[(size_t)(sb * 8 + b) * 1024 + col];
    m = fmaxf(m, pmax[(size_t)(sb * 8 + b) * 1024 + col]);
    c += pcnt[sb * 8 + b];
  }
  pooled[(size_t)b * 3072 + col] = s / c;
  pooled[(size_t)b * 3072 + 1024 + col] = m;
  pooled[(size_t)b * 3072 + 2048 + col] = X[(size_t)(b * 512) * 1024 + col];
}

// ---------- pooled GEMM stage 1: split-K partials ----------
__global__ __launch_bounds__(256) void pgemm_part(
    const float* __restrict__ P, const float* __restrict__ W,
    float* __restrict__ part) {
  __shared__ float sP[8][192];
  __shared__ float sacc[256][9];
  const int nb = blockIdx.x, kb = blockIdx.y;
  const int t = threadIdx.x;
  const int k0 = kb * 192, n0 = nb * 64;
  for (int i = t; i < 1536; i += 256)
    sP[i / 192][i % 192] = P[(size_t)(i / 192) * 3072 + k0 + i % 192];
  __syncthreads();
  const int n = t & 63, kq = t >> 6;
  float acc[8] = {};
  for (int kk = 0; kk < 48; ++kk) {
    const int k = kq * 48 + kk;
    const float wv = W[(size_t)(k0 + k) * 1024 + n0 + n];
#pragma unroll
    for (int b = 0; b < 8; ++b) acc[b] = fmaf(sP[b][k], wv, acc[b]);
  }
#pragma unroll
  for (int b = 0; b < 8; ++b) sacc[t][b] = acc[b];
  __syncthreads();
  for (int p = t; p < 512; p += 256) {
    const int b = p >> 6, nn = p & 63;
    const float v = sacc[nn][b] + sacc[64 + nn][b] + sacc[128 + nn][b] +
                    sacc[192 + nn][b];
    part[((size_t)kb * 8 + b) * 1024 + n0 + nn] = v;
  }
}

// ---------- pooled GEMM finalize ----------
__global__ __launch_bounds__(256) void pgemm_fin(
    const float* __restrict__ part, const float* __restrict__ bias,
    float* __restrict__ out) {
  const int idx = blockIdx.x * 256 + threadIdx.x;
  const int b = idx >> 10, n = idx & 1023;
  float v = bias[n];
#pragma unroll
  for (int kb = 0; kb < 16; ++kb) v += part[((size_t)kb * 8 + b) * 1024 + n];
  out[(size_t)b * 1024 + n] = v;
}

// ---------- classifier: one block per (n,b), wave-reduce over K ----------
__global__ __launch_bounds__(64) void cls_kernel(
    const float* __restrict__ X, const float* __restrict__ W,
    const float* __restrict__ bias, float* __restrict__ out) {
  const int n = blockIdx.x, b = blockIdx.y, lane = threadIdx.x;
  float a = 0.f;
#pragma unroll
  for (int i = 0; i < 16; ++i) {
    const int k = lane + i * 64;
    a = fmaf(X[(size_t)b * 1024 + k], W[(size_t)k * 20 + n], a);
  }
#pragma unroll
  for (int o = 32; o > 0; o >>= 1) a += __shfl_down(a, o, 64);
  if (lane == 0) out[b * 20 + n] = a + bias[n];
}

extern "C" void kernel_launch(void* const* d_in, const int* in_sizes, int n_in,
                              void* d_out, int out_size, void* d_ws, size_t ws_size,
                              hipStream_t stream) {
  const float* hs    = (const float*)d_in[0];
  const float* amask = (const float*)d_in[1];
  const float* Wq    = (const float*)d_in[2];
  const float* bq    = (const float*)d_in[3];
  const float* Wk    = (const float*)d_in[4];
  const float* bk    = (const float*)d_in[5];
  const float* Wv    = (const float*)d_in[6];
  const float* bv    = (const float*)d_in[7];
  const float* Wo    = (const float*)d_in[8];
  const float* bo    = (const float*)d_in[9];
  const float* ln1g  = (const float*)d_in[10];
  const float* ln1b  = (const float*)d_in[11];
  const float* W1    = (const float*)d_in[12];
  const float* b1    = (const float*)d_in[13];
  const float* W2    = (const float*)d_in[14];
  const float* b2    = (const float*)d_in[15];
  const float* ln2g  = (const float*)d_in[16];
  const float* ln2b  = (const float*)d_in[17];
  const float* rel   = (const float*)d_in[18];
  const float* poolW = (const float*)d_in[19];
  const float* poolb = (const float*)d_in[20];
  const float* plng  = (const float*)d_in[21];
  const float* plnb  = (const float*)d_in[22];
  const float* clsW  = (const float*)d_in[23];
  const float* clsb  = (const float*)d_in[24];

  char* W = (char*)d_ws;
  const size_t MB = (size_t)1 << 20;
  const size_t QK = (size_t)4096 * 1024;  // Q/K plane stride (elements)
  float* buf_t  = (float*)(W + 0 * MB);
  float* buf_t2 = (float*)(W + 16 * MB);
  float* buf_h1 = (float*)(W + 32 * MB);
  float* buf_x  = (float*)(W + 48 * MB);
  ushort* PL  = (ushort*)(W + 64 * MB);
  ushort* CTX = (ushort*)(W + 88 * MB);
  ushort* Xp  = CTX;
  ushort* H1  = (ushort*)(W + 96 * MB);
  ushort* F1  = (ushort*)(W + 104 * MB);
  ushort* Wt  = (ushort*)(W + 136 * MB);
  float* sm   = (float*)(W + 143 * MB);
  float* pooled  = sm;
  float* pool_h  = pooled + 8 * 3072;
  float* pool_h2 = pool_h + 8 * 1024;
  float* pcnt    = pool_h2 + 8 * 1024;
  float* psum    = pcnt + 64;
  float* pmax    = psum + 4 * 8 * 1024;
  float* pgpart  = pmax + 4 * 8 * 1024;

  const int n4act = (4096 * 1024) / 4;
  const dim3 gQKV(3072 / 256, 4096 / 256);  // 192 blocks, 512 thr
  const dim3 gF1(4096 / 256, 4096 / 256);   // 256 blocks, 512 thr
  const dim3 gKS(1024 / 128, 32, 2);        // 512 blocks (Wo, FFN2 split-K)
  const dim3 wsQ3(32, 32, 3);

  acast<<<n4act / 256, 256, 0, stream>>>(hs, Xp, n4act);

  const float* x_in = hs;
  for (int l = 0; l < 4; ++l) {
    const float* Wq_l = Wq + (size_t)l * 1024 * 1024;
    const float* Wk_l = Wk + (size_t)l * 1024 * 1024;
    const float* Wv_l = Wv + (size_t)l * 1024 * 1024;
    const float* Wo_l = Wo + (size_t)l * 1024 * 1024;
    const float* W1_l = W1 + (size_t)l * 1024 * 4096;
    const float* W2_l = W2 + (size_t)l * 4096 * 1024;

    // fused QKV (256^2 burst-counted tile), bias direct from bq/bk/bv
    wcast_t3<<<wsQ3, 256, 0, stream>>>(Wq_l, Wk_l, Wv_l, Wt);
    gemm256<5><<<gQKV, 512, 0, stream>>>(Xp, Wt, bq + l * 1024, bk + l * 1024,
                                         bv + l * 1024, PL, 4096, 3072, 1024);

    attn_mfma<<<dim3(32, 8, 2), 512, 0, stream>>>(
        PL, PL + QK, PL + 2 * QK, amask, rel + (size_t)l * 1023 * 32, CTX);

    wcast_t<<<dim3(32, 32), 256, 0, stream>>>(Wo_l, Wt, 1024, 1024);
    gemm_mfma<2, 2><<<gKS, 256, 0, stream>>>(CTX, Wt, bo + l * 1024, x_in,
                                             buf_t, buf_t2, nullptr, 4096, 1024, 1024);
    ln_kernel<<<4096, 256, 0, stream>>>(buf_t, buf_t2, ln1g + l * 1024,
                                        ln1b + l * 1024, buf_h1, H1);

    // FFN1 (256^2 burst-counted tile, tanh-GELU epilogue)
    wcast_t<<<dim3(4096 / 32, 1024 / 32), 256, 0, stream>>>(W1_l, Wt, 1024, 4096);
    gemm256<1><<<gF1, 512, 0, stream>>>(H1, Wt, b1 + l * 4096, nullptr, nullptr,
                                        F1, 4096, 4096, 1024);
    wcast_t<<<dim3(1024 / 32, 4096 / 32), 256, 0, stream>>>(W2_l, Wt, 4096, 1024);
    gemm_mfma<2, 2><<<gKS, 256, 0, stream>>>(F1, Wt, b2 + l * 1024, buf_h1,
                                             buf_t, buf_t2, nullptr, 4096, 1024, 4096);
    ln_kernel<<<4096, 256, 0, stream>>>(buf_t, buf_t2, ln2g + l * 1024,
                                        ln2b + l * 1024, buf_x, Xp);
    x_in = buf_x;
  }

  pool_part<<<dim3(8, 8, 4), 128, 0, stream>>>(buf_x, amask, psum, pmax, pcnt);
  pool_fin<<<32, 256, 0, stream>>>(buf_x, psum, pmax, pcnt, pooled);
  pgemm_part<<<dim3(16, 16), 256, 0, stream>>>(pooled, poolW, pgpart);
  pgemm_fin<<<32, 256, 0, stream>>>(pgpart, poolb, pool_h);
  ln_kernel<<<8, 256, 0, stream>>>(pool_h, nullptr, plng, plnb, pool_h2, nullptr);
  cls_kernel<<<dim3(20, 8), 64, 0, stream>>>(pool_h2, clsW, clsb, (float*)d_out);
}